// Round 8
// baseline (206.410 us; speedup 1.0000x reference)
//
#include <hip/hip_runtime.h>
#include <hip/hip_bf16.h>

typedef __attribute__((ext_vector_type(8))) short short8;
typedef __attribute__((ext_vector_type(4))) float float4v;

constexpr int B = 2, L = 1024, D = 256, K = 64;
constexpr int N = B * L;          // 2048 rows
constexpr int NC = L / 64;        // 16 chunks of 64 tokens
constexpr int TM_CSTRIDE = 2 * K * D;
constexpr int TM_BSTRIDE = NC * TM_CSTRIDE;

__device__ __forceinline__ ushort bf16_hi(float v) {
  return (ushort)(__float_as_uint(v) >> 16);
}
__device__ __forceinline__ float hi_f(float v) {
  return __uint_as_float(__float_as_uint(v) & 0xFFFF0000u);
}
__device__ __forceinline__ ushort bf16_rne(float v) {
  uint b = __float_as_uint(v);
  b += 0x7FFF + ((b >> 16) & 1);
  return (ushort)(b >> 16);
}

// ---------------------------------------------------------------------------
// K1: layer-1 as 3 GEMMs [2048,256]@[256,256] via MFMA bf16x3; weights
// converted fp32->bf16 hi/lo inline during staging.
// grid: g(3) x row-tile32(64) x col-half128(2) = 384 blocks, 256 threads.
__global__ __launch_bounds__(256) void enc1_kernel(
    const float* __restrict__ x, const float* __restrict__ pos_k,
    const float* __restrict__ pos_q,
    const float* __restrict__ w1_k, const float* __restrict__ w1_q,
    const float* __restrict__ wv,
    const float* __restrict__ b1_k, const float* __restrict__ b1_q,
    const float* __restrict__ bv,
    float* __restrict__ hk, float* __restrict__ hq, float* __restrict__ V) {
  __shared__ __align__(16) ushort Ah[32][40], Al[32][40];
  __shared__ __align__(16) ushort Bh[128][40], Bl[128][40];
  const int tid = threadIdx.x;
  const int g = blockIdx.x / 128;
  const int rem = blockIdx.x % 128;
  const int row0 = (rem >> 1) * 32, nb = (rem & 1) * 128;
  const float* pos = (g == 0) ? pos_k : (g == 1) ? pos_q : nullptr;
  const float* Wsrc = (g == 0) ? w1_k : (g == 1) ? w1_q : wv;
  const int w = tid >> 6, lane = tid & 63;
  const int m16 = lane & 15, quad = lane >> 4;

  float4v acc[2][2] = {};

  for (int k0 = 0; k0 < 256; k0 += 32) {
    __syncthreads();
    {  // stage A (32 rows x 32 k), built on the fly, hi/lo split
      const int r = tid >> 3, kc = (tid & 7) * 4;
      const int row = row0 + r, l = row & (L - 1);
      float4 xv = *(const float4*)&x[row * D + k0 + kc];
      if (pos) {
        const float4 pv = *(const float4*)&pos[l * D + k0 + kc];
        xv.x += pv.x; xv.y += pv.y; xv.z += pv.z; xv.w += pv.w;
      }
      ushort4 h4, l4;
      h4.x = bf16_hi(xv.x); l4.x = bf16_rne(xv.x - hi_f(xv.x));
      h4.y = bf16_hi(xv.y); l4.y = bf16_rne(xv.y - hi_f(xv.y));
      h4.z = bf16_hi(xv.z); l4.z = bf16_rne(xv.z - hi_f(xv.z));
      h4.w = bf16_hi(xv.w); l4.w = bf16_rne(xv.w - hi_f(xv.w));
      *(ushort4*)&Ah[r][kc] = h4;
      *(ushort4*)&Al[r][kc] = l4;
    }
    {  // stage B (128 n x 32 k) from fp32 weights, transpose + hi/lo split
      const int kk = tid >> 5;           // 0..7 (+p*8)
      const int n4 = (tid & 31) * 4;     // 0..124
#pragma unroll
      for (int p = 0; p < 4; ++p) {
        const int kw = p * 8 + kk;
        const float4 wv4 = *(const float4*)&Wsrc[(k0 + kw) * D + nb + n4];
        Bh[n4 + 0][kw] = bf16_hi(wv4.x); Bl[n4 + 0][kw] = bf16_rne(wv4.x - hi_f(wv4.x));
        Bh[n4 + 1][kw] = bf16_hi(wv4.y); Bl[n4 + 1][kw] = bf16_rne(wv4.y - hi_f(wv4.y));
        Bh[n4 + 2][kw] = bf16_hi(wv4.z); Bl[n4 + 2][kw] = bf16_rne(wv4.z - hi_f(wv4.z));
        Bh[n4 + 3][kw] = bf16_hi(wv4.w); Bl[n4 + 3][kw] = bf16_rne(wv4.w - hi_f(wv4.w));
      }
    }
    __syncthreads();

    short8 afh[2], afl[2], bfh[2], bfl[2];
#pragma unroll
    for (int r = 0; r < 2; ++r) {
      afh[r] = *(const short8*)&Ah[r * 16 + m16][quad * 8];
      afl[r] = *(const short8*)&Al[r * 16 + m16][quad * 8];
    }
#pragma unroll
    for (int c = 0; c < 2; ++c) {
      const int col = w * 32 + c * 16 + m16;
      bfh[c] = *(const short8*)&Bh[col][quad * 8];
      bfl[c] = *(const short8*)&Bl[col][quad * 8];
    }
#pragma unroll
    for (int r = 0; r < 2; ++r)
#pragma unroll
      for (int c = 0; c < 2; ++c) {
        acc[r][c] = __builtin_amdgcn_mfma_f32_16x16x32_bf16(afh[r], bfh[c], acc[r][c], 0, 0, 0);
        acc[r][c] = __builtin_amdgcn_mfma_f32_16x16x32_bf16(afh[r], bfl[c], acc[r][c], 0, 0, 0);
        acc[r][c] = __builtin_amdgcn_mfma_f32_16x16x32_bf16(afl[r], bfh[c], acc[r][c], 0, 0, 0);
      }
  }

  float* outp = (g == 0) ? hk : (g == 1) ? hq : V;
  const float* bp = (g == 0) ? b1_k : (g == 1) ? b1_q : bv;
#pragma unroll
  for (int c = 0; c < 2; ++c) {
    const int colg = nb + w * 32 + c * 16 + m16;
    const float bias = bp[colg];
#pragma unroll
    for (int r = 0; r < 2; ++r)
#pragma unroll
      for (int j = 0; j < 4; ++j) {
        const int rowg = row0 + r * 16 + quad * 4 + j;
        float v = acc[r][c][j] + bias;
        if (g < 2) v = 0.5f * v * (1.0f + erff(v * 0.70710678f));
        outp[rowg * D + colg] = v;
      }
  }
}

// ---------------------------------------------------------------------------
// K2: layer-2 (phase & amp GEMMs [2048,256]@[256,64]) + phasor epilogue.
// grid: enc(2) x row-tile16(128) = 256 blocks, 256 threads.
__global__ __launch_bounds__(256) void enc2_kernel(
    const float* __restrict__ x, const float* __restrict__ pos_k,
    const float* __restrict__ pos_q, const float* __restrict__ hk,
    const float* __restrict__ hq,
    const float* __restrict__ w2_k, const float* __restrict__ wa_k,
    const float* __restrict__ w2_q, const float* __restrict__ wa_q,
    const float* __restrict__ b2_k, const float* __restrict__ ba_k,
    const float* __restrict__ b2_q, const float* __restrict__ ba_q,
    float* __restrict__ kr, float* __restrict__ ki,
    float* __restrict__ qr, float* __restrict__ qi) {
  __shared__ __align__(16) ushort Ahh[16][40], Ahl[16][40], Axh[16][40], Axl[16][40];
  __shared__ __align__(16) ushort B2h[64][40], B2l[64][40], Bah[64][40], Bal[64][40];
  const int tid = threadIdx.x;
  const int e = blockIdx.x >> 7;
  const int r0g = (blockIdx.x & 127) * 16;
  const float* hsrc = e ? hq : hk;
  const float* pos = e ? pos_q : pos_k;
  const float* W2f = e ? w2_q : w2_k;
  const float* Waf = e ? wa_q : wa_k;
  const int w = tid >> 6, lane = tid & 63;
  const int m16 = lane & 15, quad = lane >> 4;

  float4v accP = {}, accA = {};
  for (int k0 = 0; k0 < 256; k0 += 32) {
    __syncthreads();
    {  // stage A: h (from global) and xa = x+pos (on the fly), hi/lo
      const int r = tid >> 4, kc = (tid & 15) * 2;
      const int row = r0g + r, l = row & (L - 1);
      const float2 hv = *(const float2*)&hsrc[row * D + k0 + kc];
      const float2 xv = *(const float2*)&x[row * D + k0 + kc];
      const float2 pv = *(const float2*)&pos[l * D + k0 + kc];
      const float a0 = xv.x + pv.x, a1 = xv.y + pv.y;
      ushort2 t;
      t.x = bf16_hi(hv.x); t.y = bf16_hi(hv.y); *(ushort2*)&Ahh[r][kc] = t;
      t.x = bf16_rne(hv.x - hi_f(hv.x)); t.y = bf16_rne(hv.y - hi_f(hv.y));
      *(ushort2*)&Ahl[r][kc] = t;
      t.x = bf16_hi(a0); t.y = bf16_hi(a1); *(ushort2*)&Axh[r][kc] = t;
      t.x = bf16_rne(a0 - hi_f(a0)); t.y = bf16_rne(a1 - hi_f(a1));
      *(ushort2*)&Axl[r][kc] = t;
    }
    {  // stage B: w2 and wa (64 n x 32 k), fp32 -> hi/lo inline
      const int n = tid & 63;
#pragma unroll
      for (int p = 0; p < 8; ++p) {
        const int kw = p * 4 + (tid >> 6);
        const float v2 = W2f[(k0 + kw) * K + n];
        const float va = Waf[(k0 + kw) * K + n];
        B2h[n][kw] = bf16_hi(v2); B2l[n][kw] = bf16_rne(v2 - hi_f(v2));
        Bah[n][kw] = bf16_hi(va); Bal[n][kw] = bf16_rne(va - hi_f(va));
      }
    }
    __syncthreads();

    const short8 ahh = *(const short8*)&Ahh[m16][quad * 8];
    const short8 ahl = *(const short8*)&Ahl[m16][quad * 8];
    const short8 axh = *(const short8*)&Axh[m16][quad * 8];
    const short8 axl = *(const short8*)&Axl[m16][quad * 8];
    const int col = w * 16 + m16;
    const short8 b2h = *(const short8*)&B2h[col][quad * 8];
    const short8 b2l = *(const short8*)&B2l[col][quad * 8];
    const short8 bah = *(const short8*)&Bah[col][quad * 8];
    const short8 bal = *(const short8*)&Bal[col][quad * 8];
    accP = __builtin_amdgcn_mfma_f32_16x16x32_bf16(ahh, b2h, accP, 0, 0, 0);
    accP = __builtin_amdgcn_mfma_f32_16x16x32_bf16(ahh, b2l, accP, 0, 0, 0);
    accP = __builtin_amdgcn_mfma_f32_16x16x32_bf16(ahl, b2h, accP, 0, 0, 0);
    accA = __builtin_amdgcn_mfma_f32_16x16x32_bf16(axh, bah, accA, 0, 0, 0);
    accA = __builtin_amdgcn_mfma_f32_16x16x32_bf16(axh, bal, accA, 0, 0, 0);
    accA = __builtin_amdgcn_mfma_f32_16x16x32_bf16(axl, bah, accA, 0, 0, 0);
  }

  float* pr = e ? qr : kr;
  float* pim = e ? qi : ki;
  const float* b2 = e ? b2_q : b2_k;
  const float* ba = e ? ba_q : ba_k;
  const int colk = w * 16 + m16;
  const float b2v = b2[colk], bav = ba[colk];
#pragma unroll
  for (int j = 0; j < 4; ++j) {
    const int row = r0g + quad * 4 + j;
    const float ph = tanhf(accP[j] + b2v) * 3.14159265358979f;
    const float av = accA[j] + bav;
    const float am = fmaxf(av, 0.0f) + log1pf(expf(-fabsf(av))) + 0.1f;
    pr[row * K + colk] = am * cosf(ph);
    pim[row * K + colk] = am * sinf(ph);
  }
}

// ---------------------------------------------------------------------------
// K3: per-chunk outer-product sums T[b][c][comp][k][d]. Grid (b,c,dc16)=512.
__global__ __launch_bounds__(256) void tbuild_kernel(
    const float* __restrict__ kr, const float* __restrict__ ki,
    const float* __restrict__ V, float* __restrict__ TM) {
  const int id = blockIdx.x;
  const int dc = id & 15, c = (id >> 4) & 15, b = id >> 8;
  const int tid = threadIdx.x;
  const int n0 = b * L + c * 64;
  const int d = dc * 16 + (tid & 15);
  const int kb = tid >> 4;

  __shared__ float krL[64][68], kiL[64][68];
  for (int e = tid; e < 1024; e += 256) {
    const int t = e >> 4, k4 = (e & 15) * 4;
    *(float4*)&krL[t][k4] = *(const float4*)&kr[(n0 + t) * K + k4];
    *(float4*)&kiL[t][k4] = *(const float4*)&ki[(n0 + t) * K + k4];
  }
  __syncthreads();

  float vcol[64];
#pragma unroll 8
  for (int t = 0; t < 64; ++t) vcol[t] = V[(n0 + t) * D + d];

  float ar[4] = {0.f, 0.f, 0.f, 0.f}, ai[4] = {0.f, 0.f, 0.f, 0.f};
#pragma unroll 4
  for (int t = 0; t < 64; ++t) {
    const float vt = vcol[t];
    const float4 k4r = *(const float4*)&krL[t][kb * 4];
    const float4 k4i = *(const float4*)&kiL[t][kb * 4];
    ar[0] += k4r.x * vt; ar[1] += k4r.y * vt; ar[2] += k4r.z * vt; ar[3] += k4r.w * vt;
    ai[0] += k4i.x * vt; ai[1] += k4i.y * vt; ai[2] += k4i.z * vt; ai[3] += k4i.w * vt;
  }

  const size_t base = (size_t)b * TM_BSTRIDE + (size_t)c * TM_CSTRIDE;
#pragma unroll
  for (int i = 0; i < 4; ++i) {
    const int k = kb * 4 + i;
    TM[base + (size_t)k * D + d] = ar[i];
    TM[base + (size_t)(K + k) * D + d] = ai[i];
  }
}

// ---------------------------------------------------------------------------
// K4: in-place exclusive prefix over c.
__global__ __launch_bounds__(256) void scan_kernel(float* __restrict__ TM) {
  const int col = blockIdx.x * 256 + threadIdx.x;
  const int d = col & 255;
  const int k = (col >> 8) & 63;
  const int comp = (col >> 14) & 1;
  const int b = col >> 15;
  size_t idx = (size_t)b * TM_BSTRIDE + (size_t)comp * (K * D) + (size_t)k * D + d;
  float run = 0.f;
#pragma unroll
  for (int c = 0; c < NC; ++c, idx += TM_CSTRIDE) {
    const float t = TM[idx];
    TM[idx] = run;
    run += t;
  }
}

// ---------------------------------------------------------------------------
// K5: fused retrieval + norm + LN + output projection + residual.
// 4 rows/block, 512 blocks, 256 threads, dual accumulators.
__global__ __launch_bounds__(256) void out_kernel(
    const float* __restrict__ qr, const float* __restrict__ qi,
    const float* __restrict__ kr, const float* __restrict__ ki,
    const float* __restrict__ V, const float* __restrict__ TM,
    const float* __restrict__ x,
    const float* __restrict__ ln_g, const float* __restrict__ ln_b,
    const float* __restrict__ wo, const float* __restrict__ bo,
    float* __restrict__ out) {
  const int tid = threadIdx.x;
  const int r0 = blockIdx.x * 4;
  const int b = r0 >> 10;
  const int l0 = r0 & (L - 1);
  const int c = l0 >> 6;
  const int lo = l0 & 63;                  // multiple of 4, 0..60
  const int n0 = b * L + c * 64;
  const int nrows = lo + 4;

  __shared__ float qrL[4][K], qiL[4][K];
  __shared__ float krL[64][68], kiL[64][68];
  __shared__ float SL[4][64];
  __shared__ float rn[4][D];
  __shared__ float red[4][2][4];

  {
    const int r = tid >> 6, k = tid & 63;  // 4*64 = 256 exactly
    qrL[r][k] = qr[(r0 + r) * K + k];
    qiL[r][k] = qi[(r0 + r) * K + k];
  }
  for (int e = tid; e < nrows * 16; e += 256) {
    const int t = e >> 4, k4 = (e & 15) * 4;
    *(float4*)&krL[t][k4] = *(const float4*)&kr[(n0 + t) * K + k4];
    *(float4*)&kiL[t][k4] = *(const float4*)&ki[(n0 + t) * K + k4];
  }
  __syncthreads();

  // intra-chunk scores: all 256 threads = 4 rq x 64 t
  {
    const int rq = tid >> 6, t = tid & 63;
    float sA = 0.f, sB = 0.f;
    if (t <= lo + rq) {
#pragma unroll
      for (int k4 = 0; k4 < K; k4 += 8) {
        const float4 a0 = *(const float4*)&qrL[rq][k4];
        const float4 b0 = *(const float4*)&qiL[rq][k4];
        const float4 k0v = *(const float4*)&krL[t][k4];
        const float4 k0i = *(const float4*)&kiL[t][k4];
        sA += a0.x * k0v.x + a0.y * k0v.y + a0.z * k0v.z + a0.w * k0v.w +
              b0.x * k0i.x + b0.y * k0i.y + b0.z * k0i.z + b0.w * k0i.w;
        const float4 a1 = *(const float4*)&qrL[rq][k4 + 4];
        const float4 b1 = *(const float4*)&qiL[rq][k4 + 4];
        const float4 k1v = *(const float4*)&krL[t][k4 + 4];
        const float4 k1i = *(const float4*)&kiL[t][k4 + 4];
        sB += a1.x * k1v.x + a1.y * k1v.y + a1.z * k1v.z + a1.w * k1v.w +
              b1.x * k1i.x + b1.y * k1i.y + b1.z * k1i.z + b1.w * k1i.w;
      }
    }
    SL[rq][t] = sA + sB;
  }
  __syncthreads();

  // main term: Re(conj(q) . M[c]) + intra-chunk S_loc . V  (column = tid)
  float accA[4] = {}, accB[4] = {};
  const float* Mr = TM + (size_t)b * TM_BSTRIDE + (size_t)c * TM_CSTRIDE;
  const float* Mi = Mr + K * D;
  for (int k4 = 0; k4 < K; k4 += 4) {
    float4 q4r[4], q4i[4];
#pragma unroll
    for (int rq = 0; rq < 4; ++rq) {
      q4r[rq] = *(const float4*)&qrL[rq][k4];
      q4i[rq] = *(const float4*)&qiL[rq][k4];
    }
#pragma unroll
    for (int j = 0; j < 4; ++j) {
      const float mr = Mr[(size_t)(k4 + j) * D + tid];
      const float mi = Mi[(size_t)(k4 + j) * D + tid];
      float* acc = (j & 1) ? accB : accA;
#pragma unroll
      for (int rq = 0; rq < 4; ++rq)
        acc[rq] += ((const float*)&q4r[rq])[j] * mr + ((const float*)&q4i[rq])[j] * mi;
    }
  }
  {
    const int tmax = lo + 3;
#pragma unroll 2
    for (int t = 0; t <= tmax; ++t) {
      const float vt = V[(n0 + t) * D + tid];
      float* acc = (t & 1) ? accB : accA;
#pragma unroll
      for (int rq = 0; rq < 4; ++rq) acc[rq] += SL[rq][t] * vt;
    }
  }

  // normalize + LN
  float val[4];
#pragma unroll
  for (int rq = 0; rq < 4; ++rq)
    val[rq] = (accA[rq] + accB[rq]) * rsqrtf((float)(l0 + rq + 1) * 64.0f);
  const int w = tid >> 6;
#pragma unroll
  for (int rq = 0; rq < 4; ++rq) {
    float v = val[rq], v2 = v * v;
    for (int off = 32; off > 0; off >>= 1) {
      v += __shfl_xor(v, off, 64);
      v2 += __shfl_xor(v2, off, 64);
    }
    if ((tid & 63) == 0) { red[rq][0][w] = v; red[rq][1][w] = v2; }
  }
  __syncthreads();

  const float g = ln_g[tid], bb = ln_b[tid];
#pragma unroll
  for (int rq = 0; rq < 4; ++rq) {
    const float s = red[rq][0][0] + red[rq][0][1] + red[rq][0][2] + red[rq][0][3];
    const float sq = red[rq][1][0] + red[rq][1][1] + red[rq][1][2] + red[rq][1][3];
    const float mu = s * (1.0f / 256.0f);
    const float var = sq * (1.0f / 256.0f) - mu * mu;
    rn[rq][tid] = (val[rq] - mu) * rsqrtf(var + 1e-5f) * g + bb;
  }
  __syncthreads();

  // out = x + rn @ wo + bo  (dual accumulators)
  float aoA[4] = {}, aoB[4] = {};
  for (int d4 = 0; d4 < D; d4 += 4) {
    float wj[4];
#pragma unroll
    for (int j = 0; j < 4; ++j) wj[j] = wo[(d4 + j) * D + tid];
    float4 rv[4];
#pragma unroll
    for (int rq = 0; rq < 4; ++rq) rv[rq] = *(const float4*)&rn[rq][d4];
#pragma unroll
    for (int rq = 0; rq < 4; ++rq) {
      aoA[rq] += rv[rq].x * wj[0] + rv[rq].z * wj[2];
      aoB[rq] += rv[rq].y * wj[1] + rv[rq].w * wj[3];
    }
  }
#pragma unroll
  for (int rq = 0; rq < 4; ++rq)
    out[(r0 + rq) * D + tid] =
        x[(r0 + rq) * D + tid] + aoA[rq] + aoB[rq] + bo[tid];
}

// ---------------------------------------------------------------------------
extern "C" void kernel_launch(void* const* d_in, const int* in_sizes, int n_in,
                              void* d_out, int out_size, void* d_ws, size_t ws_size,
                              hipStream_t stream) {
  (void)in_sizes; (void)n_in; (void)out_size; (void)ws_size;
  const float* x    = (const float*)d_in[0];
  const float* pos_k= (const float*)d_in[1];
  const float* w1_k = (const float*)d_in[2];
  const float* b1_k = (const float*)d_in[3];
  const float* w2_k = (const float*)d_in[4];
  const float* b2_k = (const float*)d_in[5];
  const float* wa_k = (const float*)d_in[6];
  const float* ba_k = (const float*)d_in[7];
  const float* pos_q= (const float*)d_in[8];
  const float* w1_q = (const float*)d_in[9];
  const float* b1_q = (const float*)d_in[10];
  const float* w2_q = (const float*)d_in[11];
  const float* b2_q = (const float*)d_in[12];
  const float* wa_q = (const float*)d_in[13];
  const float* ba_q = (const float*)d_in[14];
  const float* wv   = (const float*)d_in[15];
  const float* bv   = (const float*)d_in[16];
  const float* ln_g = (const float*)d_in[17];
  const float* ln_b = (const float*)d_in[18];
  const float* wo   = (const float*)d_in[19];
  const float* bo   = (const float*)d_in[20];

  float* ws = (float*)d_ws;
  float* kr = ws;                          // N*K
  float* ki = kr + (size_t)N * K;
  float* qr = ki + (size_t)N * K;
  float* qi = qr + (size_t)N * K;
  float* V  = qi + (size_t)N * K;          // N*D
  float* TM = V + (size_t)N * D;           // B*NC*2*K*D (4 MB)
  float* hk = TM + (size_t)B * NC * 2 * K * D;  // N*D
  float* hq = hk + (size_t)N * D;          // N*D

  enc1_kernel<<<384, 256, 0, stream>>>(x, pos_k, pos_q, w1_k, w1_q, wv,
                                       b1_k, b1_q, bv, hk, hq, V);
  enc2_kernel<<<256, 256, 0, stream>>>(x, pos_k, pos_q, hk, hq,
                                       w2_k, wa_k, w2_q, wa_q,
                                       b2_k, ba_k, b2_q, ba_q, kr, ki, qr, qi);
  tbuild_kernel<<<B * NC * 16, 256, 0, stream>>>(kr, ki, V, TM);
  scan_kernel<<<(B * 2 * K * D) / 256, 256, 0, stream>>>(TM);
  out_kernel<<<N / 4, 256, 0, stream>>>(qr, qi, kr, ki, V, TM, x,
                                        ln_g, ln_b, wo, bo, (float*)d_out);
}

// Round 9
// 182.620 us; speedup vs baseline: 1.1303x; 1.1303x over previous
//
#include <hip/hip_runtime.h>
#include <hip/hip_bf16.h>

typedef __attribute__((ext_vector_type(8))) short short8;
typedef __attribute__((ext_vector_type(4))) float float4v;

constexpr int B = 2, L = 1024, D = 256, K = 64;
constexpr int N = B * L;          // 2048 rows
constexpr int NC = L / 64;        // 16 chunks of 64 tokens
constexpr int TM_CSTRIDE = 2 * K * D;
constexpr int TM_BSTRIDE = NC * TM_CSTRIDE;

// WT arena (ushort units):
// big mats m in {w1_k, w1_q, wv, wo}: hi at m*131072, lo at +65536
// layer2 mats m in {w2_k, wa_k, w2_q, wa_q}: hi at WT2_OFF + m*32768, lo +16384
constexpr int WT2_OFF = 524288;

__device__ __forceinline__ ushort bf16_hi(float v) {
  return (ushort)(__float_as_uint(v) >> 16);
}
__device__ __forceinline__ float hi_f(float v) {
  return __uint_as_float(__float_as_uint(v) & 0xFFFF0000u);
}
__device__ __forceinline__ ushort bf16_rne(float v) {
  uint b = __float_as_uint(v);
  b += 0x7FFF + ((b >> 16) & 1);
  return (ushort)(b >> 16);
}

// ---------------------------------------------------------------------------
// K0: transpose + hi/lo split weights into WT arena (vector writes only).
// 80 blocks: 64 for four 256x256 mats (16 tiles each), 16 for four 256x64.
__global__ __launch_bounds__(256) void prep_kernel(
    const float* __restrict__ w1_k, const float* __restrict__ w1_q,
    const float* __restrict__ wv, const float* __restrict__ wo,
    const float* __restrict__ w2_k, const float* __restrict__ wa_k,
    const float* __restrict__ w2_q, const float* __restrict__ wa_q,
    ushort* __restrict__ WT) {
  __shared__ float Lt[64][65];
  const int bi = blockIdx.x, tid = threadIdx.x;
  const float* src;
  int ncols, k0, n0;
  ushort* dhi;
  int losz;
  if (bi < 64) {
    const int m = bi >> 4, t = bi & 15;
    src = (m == 0) ? w1_k : (m == 1) ? w1_q : (m == 2) ? wv : wo;
    ncols = 256; k0 = (t >> 2) * 64; n0 = (t & 3) * 64;
    dhi = WT + m * 131072; losz = 65536;
  } else {
    const int m = (bi - 64) >> 2, kt = (bi - 64) & 3;
    src = (m == 0) ? w2_k : (m == 1) ? wa_k : (m == 2) ? w2_q : wa_q;
    ncols = 64; k0 = kt * 64; n0 = 0;
    dhi = WT + WT2_OFF + m * 32768; losz = 16384;
  }
  ushort* dlo = dhi + losz;
  for (int p = 0; p < 16; ++p) {
    const int kr = p * 4 + (tid >> 6), nc = tid & 63;
    Lt[kr][nc] = src[(k0 + kr) * ncols + n0 + nc];
  }
  __syncthreads();
  const int n = tid >> 2, kq = tid & 3;
  uint uh[8], ul[8];
  for (int i = 0; i < 8; ++i) {
    const float v0 = Lt[kq * 16 + 2 * i][n];
    const float v1 = Lt[kq * 16 + 2 * i + 1][n];
    uh[i] = (uint)bf16_hi(v0) | ((uint)bf16_hi(v1) << 16);
    ul[i] = (uint)bf16_rne(v0 - hi_f(v0)) | ((uint)bf16_rne(v1 - hi_f(v1)) << 16);
  }
  const int oidx = (n0 + n) * 256 + k0 + kq * 16;
  *(uint4*)&dhi[oidx] = make_uint4(uh[0], uh[1], uh[2], uh[3]);
  *(uint4*)&dhi[oidx + 8] = make_uint4(uh[4], uh[5], uh[6], uh[7]);
  *(uint4*)&dlo[oidx] = make_uint4(ul[0], ul[1], ul[2], ul[3]);
  *(uint4*)&dlo[oidx + 8] = make_uint4(ul[4], ul[5], ul[6], ul[7]);
}

// ---------------------------------------------------------------------------
// K1: layer-1 as 3 GEMMs [2048,256]@[256,256] via MFMA bf16x3.
// grid: g(3) x row-tile32(64) x col-half128(2) = 384 blocks, 256 threads.
__global__ __launch_bounds__(256) void enc1_kernel(
    const float* __restrict__ x, const float* __restrict__ pos_k,
    const float* __restrict__ pos_q,
    const float* __restrict__ b1_k, const float* __restrict__ b1_q,
    const float* __restrict__ bv, const ushort* __restrict__ WT,
    float* __restrict__ hk, float* __restrict__ hq, float* __restrict__ V) {
  __shared__ __align__(16) ushort Ah[32][40], Al[32][40];
  __shared__ __align__(16) ushort Bh[128][40], Bl[128][40];
  const int tid = threadIdx.x;
  const int g = blockIdx.x / 128;
  const int rem = blockIdx.x % 128;
  const int row0 = (rem >> 1) * 32, nb = (rem & 1) * 128;
  const float* pos = (g == 0) ? pos_k : (g == 1) ? pos_q : nullptr;
  const ushort* Wh = WT + g * 131072;
  const ushort* Wl = Wh + 65536;
  const int w = tid >> 6, lane = tid & 63;
  const int m16 = lane & 15, quad = lane >> 4;

  float4v acc[2][2] = {};

  for (int k0 = 0; k0 < 256; k0 += 32) {
    __syncthreads();
    {  // stage A (32 rows x 32 k), built on the fly, hi/lo split
      const int r = tid >> 3, kc = (tid & 7) * 4;
      const int row = row0 + r, l = row & (L - 1);
      float4 xv = *(const float4*)&x[row * D + k0 + kc];
      if (pos) {
        const float4 pv = *(const float4*)&pos[l * D + k0 + kc];
        xv.x += pv.x; xv.y += pv.y; xv.z += pv.z; xv.w += pv.w;
      }
      ushort4 h4, l4;
      h4.x = bf16_hi(xv.x); l4.x = bf16_rne(xv.x - hi_f(xv.x));
      h4.y = bf16_hi(xv.y); l4.y = bf16_rne(xv.y - hi_f(xv.y));
      h4.z = bf16_hi(xv.z); l4.z = bf16_rne(xv.z - hi_f(xv.z));
      h4.w = bf16_hi(xv.w); l4.w = bf16_rne(xv.w - hi_f(xv.w));
      *(ushort4*)&Ah[r][kc] = h4;
      *(ushort4*)&Al[r][kc] = l4;
    }
#pragma unroll
    for (int p = 0; p < 2; ++p) {  // stage B (128 n x 32 k) from WT planes
      const int n = (tid >> 2) + p * 64, chunk = tid & 3;
      const int ga = (nb + n) * 256 + k0 + chunk * 8;
      *(uint4*)&Bh[n][chunk * 8] = *(const uint4*)&Wh[ga];
      *(uint4*)&Bl[n][chunk * 8] = *(const uint4*)&Wl[ga];
    }
    __syncthreads();

    short8 afh[2], afl[2], bfh[2], bfl[2];
#pragma unroll
    for (int r = 0; r < 2; ++r) {
      afh[r] = *(const short8*)&Ah[r * 16 + m16][quad * 8];
      afl[r] = *(const short8*)&Al[r * 16 + m16][quad * 8];
    }
#pragma unroll
    for (int c = 0; c < 2; ++c) {
      const int col = w * 32 + c * 16 + m16;
      bfh[c] = *(const short8*)&Bh[col][quad * 8];
      bfl[c] = *(const short8*)&Bl[col][quad * 8];
    }
#pragma unroll
    for (int r = 0; r < 2; ++r)
#pragma unroll
      for (int c = 0; c < 2; ++c) {
        acc[r][c] = __builtin_amdgcn_mfma_f32_16x16x32_bf16(afh[r], bfh[c], acc[r][c], 0, 0, 0);
        acc[r][c] = __builtin_amdgcn_mfma_f32_16x16x32_bf16(afh[r], bfl[c], acc[r][c], 0, 0, 0);
        acc[r][c] = __builtin_amdgcn_mfma_f32_16x16x32_bf16(afl[r], bfh[c], acc[r][c], 0, 0, 0);
      }
  }

  float* outp = (g == 0) ? hk : (g == 1) ? hq : V;
  const float* bp = (g == 0) ? b1_k : (g == 1) ? b1_q : bv;
#pragma unroll
  for (int c = 0; c < 2; ++c) {
    const int colg = nb + w * 32 + c * 16 + m16;
    const float bias = bp[colg];
#pragma unroll
    for (int r = 0; r < 2; ++r)
#pragma unroll
      for (int j = 0; j < 4; ++j) {
        const int rowg = row0 + r * 16 + quad * 4 + j;
        float v = acc[r][c][j] + bias;
        if (g < 2) v = 0.5f * v * (1.0f + erff(v * 0.70710678f));
        outp[rowg * D + colg] = v;
      }
  }
}

// ---------------------------------------------------------------------------
// K2: layer-2 (phase & amp GEMMs [2048,256]@[256,64]) + phasor epilogue.
// grid: enc(2) x row-tile16(128) = 256 blocks, 256 threads.
__global__ __launch_bounds__(256) void enc2_kernel(
    const float* __restrict__ x, const float* __restrict__ pos_k,
    const float* __restrict__ pos_q, const float* __restrict__ hk,
    const float* __restrict__ hq,
    const float* __restrict__ b2_k, const float* __restrict__ ba_k,
    const float* __restrict__ b2_q, const float* __restrict__ ba_q,
    const ushort* __restrict__ WT,
    float* __restrict__ kr, float* __restrict__ ki,
    float* __restrict__ qr, float* __restrict__ qi) {
  __shared__ __align__(16) ushort Ahh[16][40], Ahl[16][40], Axh[16][40], Axl[16][40];
  __shared__ __align__(16) ushort B2h[64][40], B2l[64][40], Bah[64][40], Bal[64][40];
  const int tid = threadIdx.x;
  const int e = blockIdx.x >> 7;
  const int r0g = (blockIdx.x & 127) * 16;
  const float* hsrc = e ? hq : hk;
  const float* pos = e ? pos_q : pos_k;
  const ushort* W2h = WT + WT2_OFF + (e ? 2 : 0) * 32768;
  const ushort* W2l = W2h + 16384;
  const ushort* Wah = WT + WT2_OFF + (e ? 3 : 1) * 32768;
  const ushort* Wal = Wah + 16384;
  const int w = tid >> 6, lane = tid & 63;
  const int m16 = lane & 15, quad = lane >> 4;

  float4v accP = {}, accA = {};
  for (int k0 = 0; k0 < 256; k0 += 32) {
    __syncthreads();
    {  // stage A: h (from global) and xa = x+pos (on the fly), hi/lo
      const int r = tid >> 4, kc = (tid & 15) * 2;
      const int row = r0g + r, l = row & (L - 1);
      const float2 hv = *(const float2*)&hsrc[row * D + k0 + kc];
      const float2 xv = *(const float2*)&x[row * D + k0 + kc];
      const float2 pv = *(const float2*)&pos[l * D + k0 + kc];
      const float a0 = xv.x + pv.x, a1 = xv.y + pv.y;
      ushort2 t;
      t.x = bf16_hi(hv.x); t.y = bf16_hi(hv.y); *(ushort2*)&Ahh[r][kc] = t;
      t.x = bf16_rne(hv.x - hi_f(hv.x)); t.y = bf16_rne(hv.y - hi_f(hv.y));
      *(ushort2*)&Ahl[r][kc] = t;
      t.x = bf16_hi(a0); t.y = bf16_hi(a1); *(ushort2*)&Axh[r][kc] = t;
      t.x = bf16_rne(a0 - hi_f(a0)); t.y = bf16_rne(a1 - hi_f(a1));
      *(ushort2*)&Axl[r][kc] = t;
    }
    {  // stage B: w2 and wa hi/lo (64 n x 32 k each), vector loads from WT
      const int n = tid >> 2, chunk = tid & 3;
      const int ga = n * 256 + k0 + chunk * 8;
      *(uint4*)&B2h[n][chunk * 8] = *(const uint4*)&W2h[ga];
      *(uint4*)&B2l[n][chunk * 8] = *(const uint4*)&W2l[ga];
      *(uint4*)&Bah[n][chunk * 8] = *(const uint4*)&Wah[ga];
      *(uint4*)&Bal[n][chunk * 8] = *(const uint4*)&Wal[ga];
    }
    __syncthreads();

    const short8 ahh = *(const short8*)&Ahh[m16][quad * 8];
    const short8 ahl = *(const short8*)&Ahl[m16][quad * 8];
    const short8 axh = *(const short8*)&Axh[m16][quad * 8];
    const short8 axl = *(const short8*)&Axl[m16][quad * 8];
    const int col = w * 16 + m16;
    const short8 b2h = *(const short8*)&B2h[col][quad * 8];
    const short8 b2l = *(const short8*)&B2l[col][quad * 8];
    const short8 bah = *(const short8*)&Bah[col][quad * 8];
    const short8 bal = *(const short8*)&Bal[col][quad * 8];
    accP = __builtin_amdgcn_mfma_f32_16x16x32_bf16(ahh, b2h, accP, 0, 0, 0);
    accP = __builtin_amdgcn_mfma_f32_16x16x32_bf16(ahh, b2l, accP, 0, 0, 0);
    accP = __builtin_amdgcn_mfma_f32_16x16x32_bf16(ahl, b2h, accP, 0, 0, 0);
    accA = __builtin_amdgcn_mfma_f32_16x16x32_bf16(axh, bah, accA, 0, 0, 0);
    accA = __builtin_amdgcn_mfma_f32_16x16x32_bf16(axh, bal, accA, 0, 0, 0);
    accA = __builtin_amdgcn_mfma_f32_16x16x32_bf16(axl, bah, accA, 0, 0, 0);
  }

  float* pr = e ? qr : kr;
  float* pim = e ? qi : ki;
  const float* b2 = e ? b2_q : b2_k;
  const float* ba = e ? ba_q : ba_k;
  const int colk = w * 16 + m16;
  const float b2v = b2[colk], bav = ba[colk];
#pragma unroll
  for (int j = 0; j < 4; ++j) {
    const int row = r0g + quad * 4 + j;
    const float ph = tanhf(accP[j] + b2v) * 3.14159265358979f;
    const float av = accA[j] + bav;
    const float am = fmaxf(av, 0.0f) + log1pf(expf(-fabsf(av))) + 0.1f;
    pr[row * K + colk] = am * cosf(ph);
    pim[row * K + colk] = am * sinf(ph);
  }
}

// ---------------------------------------------------------------------------
// K3: per-chunk outer-product sums T[b][c][comp][k][d]. Grid (b,c,dc16)=512.
__global__ __launch_bounds__(256) void tbuild_kernel(
    const float* __restrict__ kr, const float* __restrict__ ki,
    const float* __restrict__ V, float* __restrict__ TM) {
  const int id = blockIdx.x;
  const int dc = id & 15, c = (id >> 4) & 15, b = id >> 8;
  const int tid = threadIdx.x;
  const int n0 = b * L + c * 64;
  const int d = dc * 16 + (tid & 15);
  const int kb = tid >> 4;

  __shared__ float krL[64][68], kiL[64][68];
  for (int e = tid; e < 1024; e += 256) {
    const int t = e >> 4, k4 = (e & 15) * 4;
    *(float4*)&krL[t][k4] = *(const float4*)&kr[(n0 + t) * K + k4];
    *(float4*)&kiL[t][k4] = *(const float4*)&ki[(n0 + t) * K + k4];
  }
  __syncthreads();

  float vcol[64];
#pragma unroll 8
  for (int t = 0; t < 64; ++t) vcol[t] = V[(n0 + t) * D + d];

  float ar[4] = {0.f, 0.f, 0.f, 0.f}, ai[4] = {0.f, 0.f, 0.f, 0.f};
#pragma unroll 4
  for (int t = 0; t < 64; ++t) {
    const float vt = vcol[t];
    const float4 k4r = *(const float4*)&krL[t][kb * 4];
    const float4 k4i = *(const float4*)&kiL[t][kb * 4];
    ar[0] += k4r.x * vt; ar[1] += k4r.y * vt; ar[2] += k4r.z * vt; ar[3] += k4r.w * vt;
    ai[0] += k4i.x * vt; ai[1] += k4i.y * vt; ai[2] += k4i.z * vt; ai[3] += k4i.w * vt;
  }

  const size_t base = (size_t)b * TM_BSTRIDE + (size_t)c * TM_CSTRIDE;
#pragma unroll
  for (int i = 0; i < 4; ++i) {
    const int k = kb * 4 + i;
    TM[base + (size_t)k * D + d] = ar[i];
    TM[base + (size_t)(K + k) * D + d] = ai[i];
  }
}

// ---------------------------------------------------------------------------
// K4: in-place exclusive prefix over c.
__global__ __launch_bounds__(256) void scan_kernel(float* __restrict__ TM) {
  const int col = blockIdx.x * 256 + threadIdx.x;
  const int d = col & 255;
  const int k = (col >> 8) & 63;
  const int comp = (col >> 14) & 1;
  const int b = col >> 15;
  size_t idx = (size_t)b * TM_BSTRIDE + (size_t)comp * (K * D) + (size_t)k * D + d;
  float run = 0.f;
#pragma unroll
  for (int c = 0; c < NC; ++c, idx += TM_CSTRIDE) {
    const float t = TM[idx];
    TM[idx] = run;
    run += t;
  }
}

// ---------------------------------------------------------------------------
// K5: retrieval + norm + LN -> rn ([N,D] fp32, reuses hk buffer).
// 4 rows/block, 512 blocks, 256 threads. Compile-time dual accumulators.
__global__ __launch_bounds__(256) void out_retr_kernel(
    const float* __restrict__ qr, const float* __restrict__ qi,
    const float* __restrict__ kr, const float* __restrict__ ki,
    const float* __restrict__ V, const float* __restrict__ TM,
    const float* __restrict__ ln_g, const float* __restrict__ ln_b,
    float* __restrict__ rnG) {
  const int tid = threadIdx.x;
  const int r0 = blockIdx.x * 4;
  const int b = r0 >> 10;
  const int l0 = r0 & (L - 1);
  const int c = l0 >> 6;
  const int lo = l0 & 63;                  // multiple of 4, 0..60
  const int n0 = b * L + c * 64;
  const int nrows = lo + 4;

  __shared__ float qrL[4][K], qiL[4][K];
  __shared__ float krL[64][68], kiL[64][68];
  __shared__ float SL[4][64];
  __shared__ float red[4][2][4];

  {
    const int r = tid >> 6, k = tid & 63;  // 4*64 = 256 exactly
    qrL[r][k] = qr[(r0 + r) * K + k];
    qiL[r][k] = qi[(r0 + r) * K + k];
  }
  for (int e = tid; e < nrows * 16; e += 256) {
    const int t = e >> 4, k4 = (e & 15) * 4;
    *(float4*)&krL[t][k4] = *(const float4*)&kr[(n0 + t) * K + k4];
    *(float4*)&kiL[t][k4] = *(const float4*)&ki[(n0 + t) * K + k4];
  }
  __syncthreads();

  // intra-chunk scores: 256 threads = 4 rq x 64 t
  {
    const int rq = tid >> 6, t = tid & 63;
    float sA = 0.f, sB = 0.f;
    if (t <= lo + rq) {
#pragma unroll
      for (int k4 = 0; k4 < K; k4 += 8) {
        const float4 a0 = *(const float4*)&qrL[rq][k4];
        const float4 b0 = *(const float4*)&qiL[rq][k4];
        const float4 k0v = *(const float4*)&krL[t][k4];
        const float4 k0i = *(const float4*)&kiL[t][k4];
        sA += a0.x * k0v.x + a0.y * k0v.y + a0.z * k0v.z + a0.w * k0v.w +
              b0.x * k0i.x + b0.y * k0i.y + b0.z * k0i.z + b0.w * k0i.w;
        const float4 a1 = *(const float4*)&qrL[rq][k4 + 4];
        const float4 b1 = *(const float4*)&qiL[rq][k4 + 4];
        const float4 k1v = *(const float4*)&krL[t][k4 + 4];
        const float4 k1i = *(const float4*)&kiL[t][k4 + 4];
        sB += a1.x * k1v.x + a1.y * k1v.y + a1.z * k1v.z + a1.w * k1v.w +
              b1.x * k1i.x + b1.y * k1i.y + b1.z * k1i.z + b1.w * k1i.w;
      }
    }
    SL[rq][t] = sA + sB;
  }
  __syncthreads();

  // main term: Re(conj(q) . M[c])  (column = tid); j-parity dual accumulators
  float accA[4] = {}, accB[4] = {};
  const float* Mr = TM + (size_t)b * TM_BSTRIDE + (size_t)c * TM_CSTRIDE;
  const float* Mi = Mr + K * D;
  for (int k4 = 0; k4 < K; k4 += 4) {
    float4 q4r[4], q4i[4];
#pragma unroll
    for (int rq = 0; rq < 4; ++rq) {
      q4r[rq] = *(const float4*)&qrL[rq][k4];
      q4i[rq] = *(const float4*)&qiL[rq][k4];
    }
    float mr[4], mi[4];
#pragma unroll
    for (int j = 0; j < 4; ++j) {
      mr[j] = Mr[(size_t)(k4 + j) * D + tid];
      mi[j] = Mi[(size_t)(k4 + j) * D + tid];
    }
#pragma unroll
    for (int rq = 0; rq < 4; ++rq) {
      accA[rq] += ((const float*)&q4r[rq])[0] * mr[0] + ((const float*)&q4i[rq])[0] * mi[0]
                + ((const float*)&q4r[rq])[2] * mr[2] + ((const float*)&q4i[rq])[2] * mi[2];
      accB[rq] += ((const float*)&q4r[rq])[1] * mr[1] + ((const float*)&q4i[rq])[1] * mi[1]
                + ((const float*)&q4r[rq])[3] * mr[3] + ((const float*)&q4i[rq])[3] * mi[3];
    }
  }
  // intra-chunk S_loc . V, t-pairs (tmax = lo+3 is odd -> full pairs)
  {
    const int tmax = lo + 3;
    for (int t = 0; t < tmax; t += 2) {
      const float vt0 = V[(n0 + t) * D + tid];
      const float vt1 = V[(n0 + t + 1) * D + tid];
#pragma unroll
      for (int rq = 0; rq < 4; ++rq) {
        accA[rq] += SL[rq][t] * vt0;
        accB[rq] += SL[rq][t + 1] * vt1;
      }
    }
  }

  // normalize + LN
  float val[4];
#pragma unroll
  for (int rq = 0; rq < 4; ++rq)
    val[rq] = (accA[rq] + accB[rq]) * rsqrtf((float)(l0 + rq + 1) * 64.0f);
  const int w = tid >> 6;
#pragma unroll
  for (int rq = 0; rq < 4; ++rq) {
    float v = val[rq], v2 = v * v;
    for (int off = 32; off > 0; off >>= 1) {
      v += __shfl_xor(v, off, 64);
      v2 += __shfl_xor(v2, off, 64);
    }
    if ((tid & 63) == 0) { red[rq][0][w] = v; red[rq][1][w] = v2; }
  }
  __syncthreads();

  const float g = ln_g[tid], bb = ln_b[tid];
#pragma unroll
  for (int rq = 0; rq < 4; ++rq) {
    const float s = red[rq][0][0] + red[rq][0][1] + red[rq][0][2] + red[rq][0][3];
    const float sq = red[rq][1][0] + red[rq][1][1] + red[rq][1][2] + red[rq][1][3];
    const float mu = s * (1.0f / 256.0f);
    const float var = sq * (1.0f / 256.0f) - mu * mu;
    rnG[(r0 + rq) * D + tid] = (val[rq] - mu) * rsqrtf(var + 1e-5f) * g + bb;
  }
}

// ---------------------------------------------------------------------------
// K6: out = x + rn @ wo + bo via MFMA bf16x3.
// grid: row-tile32(64) x col-quarter64(4) = 256 blocks, 256 threads.
__global__ __launch_bounds__(256) void out_gemm_kernel(
    const float* __restrict__ rnG, const float* __restrict__ x,
    const float* __restrict__ bo, const ushort* __restrict__ WT,
    float* __restrict__ out) {
  __shared__ __align__(16) ushort Ah[32][40], Al[32][40];
  __shared__ __align__(16) ushort Bh[64][40], Bl[64][40];
  const int tid = threadIdx.x;
  const int row0 = (blockIdx.x >> 2) * 32, nb = (blockIdx.x & 3) * 64;
  const ushort* Wh = WT + 3 * 131072;   // wo planes
  const ushort* Wl = Wh + 65536;
  const int w = tid >> 6, lane = tid & 63;
  const int m16 = lane & 15, quad = lane >> 4;

  float4v acc[2] = {};

  for (int k0 = 0; k0 < 256; k0 += 32) {
    __syncthreads();
    {  // stage A (32 rows x 32 k) from rn, hi/lo split (row-layout, vector writes)
      const int r = tid >> 3, kc = (tid & 7) * 4;
      const float4 xv = *(const float4*)&rnG[(row0 + r) * D + k0 + kc];
      ushort4 h4, l4;
      h4.x = bf16_hi(xv.x); l4.x = bf16_rne(xv.x - hi_f(xv.x));
      h4.y = bf16_hi(xv.y); l4.y = bf16_rne(xv.y - hi_f(xv.y));
      h4.z = bf16_hi(xv.z); l4.z = bf16_rne(xv.z - hi_f(xv.z));
      h4.w = bf16_hi(xv.w); l4.w = bf16_rne(xv.w - hi_f(xv.w));
      *(ushort4*)&Ah[r][kc] = h4;
      *(ushort4*)&Al[r][kc] = l4;
    }
    {  // stage B (64 n x 32 k) from WT wo planes
      const int n = tid >> 2, chunk = tid & 3;
      const int ga = (nb + n) * 256 + k0 + chunk * 8;
      *(uint4*)&Bh[n][chunk * 8] = *(const uint4*)&Wh[ga];
      *(uint4*)&Bl[n][chunk * 8] = *(const uint4*)&Wl[ga];
    }
    __syncthreads();

    short8 afh[2], afl[2];
#pragma unroll
    for (int r = 0; r < 2; ++r) {
      afh[r] = *(const short8*)&Ah[r * 16 + m16][quad * 8];
      afl[r] = *(const short8*)&Al[r * 16 + m16][quad * 8];
    }
    const int col = w * 16 + m16;
    const short8 bfh = *(const short8*)&Bh[col][quad * 8];
    const short8 bfl = *(const short8*)&Bl[col][quad * 8];
#pragma unroll
    for (int r = 0; r < 2; ++r) {
      acc[r] = __builtin_amdgcn_mfma_f32_16x16x32_bf16(afh[r], bfh, acc[r], 0, 0, 0);
      acc[r] = __builtin_amdgcn_mfma_f32_16x16x32_bf16(afh[r], bfl, acc[r], 0, 0, 0);
      acc[r] = __builtin_amdgcn_mfma_f32_16x16x32_bf16(afl[r], bfh, acc[r], 0, 0, 0);
    }
  }

  const int colg = nb + w * 16 + m16;
  const float bias = bo[colg];
#pragma unroll
  for (int r = 0; r < 2; ++r)
#pragma unroll
    for (int j = 0; j < 4; ++j) {
      const int rowg = row0 + r * 16 + quad * 4 + j;
      out[rowg * D + colg] = x[rowg * D + colg] + acc[r][j] + bias;
    }
}

// ---------------------------------------------------------------------------
extern "C" void kernel_launch(void* const* d_in, const int* in_sizes, int n_in,
                              void* d_out, int out_size, void* d_ws, size_t ws_size,
                              hipStream_t stream) {
  (void)in_sizes; (void)n_in; (void)out_size; (void)ws_size;
  const float* x    = (const float*)d_in[0];
  const float* pos_k= (const float*)d_in[1];
  const float* w1_k = (const float*)d_in[2];
  const float* b1_k = (const float*)d_in[3];
  const float* w2_k = (const float*)d_in[4];
  const float* b2_k = (const float*)d_in[5];
  const float* wa_k = (const float*)d_in[6];
  const float* ba_k = (const float*)d_in[7];
  const float* pos_q= (const float*)d_in[8];
  const float* w1_q = (const float*)d_in[9];
  const float* b1_q = (const float*)d_in[10];
  const float* w2_q = (const float*)d_in[11];
  const float* b2_q = (const float*)d_in[12];
  const float* wa_q = (const float*)d_in[13];
  const float* ba_q = (const float*)d_in[14];
  const float* wv   = (const float*)d_in[15];
  const float* bv   = (const float*)d_in[16];
  const float* ln_g = (const float*)d_in[17];
  const float* ln_b = (const float*)d_in[18];
  const float* wo   = (const float*)d_in[19];
  const float* bo   = (const float*)d_in[20];

  float* ws = (float*)d_ws;
  float* kr = ws;                          // N*K
  float* ki = kr + (size_t)N * K;
  float* qr = ki + (size_t)N * K;
  float* qi = qr + (size_t)N * K;
  float* V  = qi + (size_t)N * K;          // N*D
  float* TM = V + (size_t)N * D;           // B*NC*2*K*D (4 MB)
  float* hk = TM + (size_t)B * NC * 2 * K * D;  // N*D (later reused as rn)
  float* hq = hk + (size_t)N * D;          // N*D
  ushort* WT = (ushort*)(hq + (size_t)N * D);   // 655360 ushorts (1.31 MB)
  float* rn = hk;                          // reuse (hk dead after enc2)

  prep_kernel<<<80, 256, 0, stream>>>(w1_k, w1_q, wv, wo,
                                      w2_k, wa_k, w2_q, wa_q, WT);
  enc1_kernel<<<384, 256, 0, stream>>>(x, pos_k, pos_q, b1_k, b1_q, bv, WT,
                                       hk, hq, V);
  enc2_kernel<<<256, 256, 0, stream>>>(x, pos_k, pos_q, hk, hq,
                                       b2_k, ba_k, b2_q, ba_q, WT,
                                       kr, ki, qr, qi);
  tbuild_kernel<<<B * NC * 16, 256, 0, stream>>>(kr, ki, V, TM);
  scan_kernel<<<(B * 2 * K * D) / 256, 256, 0, stream>>>(TM);
  out_retr_kernel<<<N / 4, 256, 0, stream>>>(qr, qi, kr, ki, V, TM,
                                             ln_g, ln_b, rn);
  out_gemm_kernel<<<256, 256, 0, stream>>>(rn, x, bo, WT, (float*)d_out);
}

// Round 10
// 175.372 us; speedup vs baseline: 1.1770x; 1.0413x over previous
//
#include <hip/hip_runtime.h>
#include <hip/hip_bf16.h>

typedef __attribute__((ext_vector_type(8))) short short8;
typedef __attribute__((ext_vector_type(4))) float float4v;

constexpr int B = 2, L = 1024, D = 256, K = 64;
constexpr int N = B * L;          // 2048 rows
constexpr int NC = L / 64;        // 16 chunks of 64 tokens
constexpr int TM_CSTRIDE = 2 * K * D;
constexpr int TM_BSTRIDE = NC * TM_CSTRIDE;

// WT arena (ushort units):
// big mats m in {w1_k, w1_q, wv, wo}: hi at m*131072, lo at +65536
// layer2 mats m in {w2_k, wa_k, w2_q, wa_q}: hi at WT2_OFF + m*32768, lo +16384
constexpr int WT2_OFF = 524288;

__device__ __forceinline__ ushort bf16_hi(float v) {
  return (ushort)(__float_as_uint(v) >> 16);
}
__device__ __forceinline__ float hi_f(float v) {
  return __uint_as_float(__float_as_uint(v) & 0xFFFF0000u);
}
__device__ __forceinline__ ushort bf16_rne(float v) {
  uint b = __float_as_uint(v);
  b += 0x7FFF + ((b >> 16) & 1);
  return (ushort)(b >> 16);
}

// ---------------------------------------------------------------------------
// K0: transpose + hi/lo split weights into WT arena (vector writes only).
__global__ __launch_bounds__(256) void prep_kernel(
    const float* __restrict__ w1_k, const float* __restrict__ w1_q,
    const float* __restrict__ wv, const float* __restrict__ wo,
    const float* __restrict__ w2_k, const float* __restrict__ wa_k,
    const float* __restrict__ w2_q, const float* __restrict__ wa_q,
    ushort* __restrict__ WT) {
  __shared__ float Lt[64][65];
  const int bi = blockIdx.x, tid = threadIdx.x;
  const float* src;
  int ncols, k0, n0;
  ushort* dhi;
  int losz;
  if (bi < 64) {
    const int m = bi >> 4, t = bi & 15;
    src = (m == 0) ? w1_k : (m == 1) ? w1_q : (m == 2) ? wv : wo;
    ncols = 256; k0 = (t >> 2) * 64; n0 = (t & 3) * 64;
    dhi = WT + m * 131072; losz = 65536;
  } else {
    const int m = (bi - 64) >> 2, kt = (bi - 64) & 3;
    src = (m == 0) ? w2_k : (m == 1) ? wa_k : (m == 2) ? w2_q : wa_q;
    ncols = 64; k0 = kt * 64; n0 = 0;
    dhi = WT + WT2_OFF + m * 32768; losz = 16384;
  }
  ushort* dlo = dhi + losz;
  for (int p = 0; p < 16; ++p) {
    const int kr = p * 4 + (tid >> 6), nc = tid & 63;
    Lt[kr][nc] = src[(k0 + kr) * ncols + n0 + nc];
  }
  __syncthreads();
  const int n = tid >> 2, kq = tid & 3;
  uint uh[8], ul[8];
  for (int i = 0; i < 8; ++i) {
    const float v0 = Lt[kq * 16 + 2 * i][n];
    const float v1 = Lt[kq * 16 + 2 * i + 1][n];
    uh[i] = (uint)bf16_hi(v0) | ((uint)bf16_hi(v1) << 16);
    ul[i] = (uint)bf16_rne(v0 - hi_f(v0)) | ((uint)bf16_rne(v1 - hi_f(v1)) << 16);
  }
  const int oidx = (n0 + n) * 256 + k0 + kq * 16;
  *(uint4*)&dhi[oidx] = make_uint4(uh[0], uh[1], uh[2], uh[3]);
  *(uint4*)&dhi[oidx + 8] = make_uint4(uh[4], uh[5], uh[6], uh[7]);
  *(uint4*)&dlo[oidx] = make_uint4(ul[0], ul[1], ul[2], ul[3]);
  *(uint4*)&dlo[oidx + 8] = make_uint4(ul[4], ul[5], ul[6], ul[7]);
}

// ---------------------------------------------------------------------------
// K1: layer-1 as 3 GEMMs [2048,256]@[256,256] via MFMA bf16x3.
__global__ __launch_bounds__(256) void enc1_kernel(
    const float* __restrict__ x, const float* __restrict__ pos_k,
    const float* __restrict__ pos_q,
    const float* __restrict__ b1_k, const float* __restrict__ b1_q,
    const float* __restrict__ bv, const ushort* __restrict__ WT,
    float* __restrict__ hk, float* __restrict__ hq, float* __restrict__ V) {
  __shared__ __align__(16) ushort Ah[32][40], Al[32][40];
  __shared__ __align__(16) ushort Bh[128][40], Bl[128][40];
  const int tid = threadIdx.x;
  const int g = blockIdx.x / 128;
  const int rem = blockIdx.x % 128;
  const int row0 = (rem >> 1) * 32, nb = (rem & 1) * 128;
  const float* pos = (g == 0) ? pos_k : (g == 1) ? pos_q : nullptr;
  const ushort* Wh = WT + g * 131072;
  const ushort* Wl = Wh + 65536;
  const int w = tid >> 6, lane = tid & 63;
  const int m16 = lane & 15, quad = lane >> 4;

  float4v acc[2][2] = {};

  for (int k0 = 0; k0 < 256; k0 += 32) {
    __syncthreads();
    {
      const int r = tid >> 3, kc = (tid & 7) * 4;
      const int row = row0 + r, l = row & (L - 1);
      float4 xv = *(const float4*)&x[row * D + k0 + kc];
      if (pos) {
        const float4 pv = *(const float4*)&pos[l * D + k0 + kc];
        xv.x += pv.x; xv.y += pv.y; xv.z += pv.z; xv.w += pv.w;
      }
      ushort4 h4, l4;
      h4.x = bf16_hi(xv.x); l4.x = bf16_rne(xv.x - hi_f(xv.x));
      h4.y = bf16_hi(xv.y); l4.y = bf16_rne(xv.y - hi_f(xv.y));
      h4.z = bf16_hi(xv.z); l4.z = bf16_rne(xv.z - hi_f(xv.z));
      h4.w = bf16_hi(xv.w); l4.w = bf16_rne(xv.w - hi_f(xv.w));
      *(ushort4*)&Ah[r][kc] = h4;
      *(ushort4*)&Al[r][kc] = l4;
    }
#pragma unroll
    for (int p = 0; p < 2; ++p) {
      const int n = (tid >> 2) + p * 64, chunk = tid & 3;
      const int ga = (nb + n) * 256 + k0 + chunk * 8;
      *(uint4*)&Bh[n][chunk * 8] = *(const uint4*)&Wh[ga];
      *(uint4*)&Bl[n][chunk * 8] = *(const uint4*)&Wl[ga];
    }
    __syncthreads();

    short8 afh[2], afl[2], bfh[2], bfl[2];
#pragma unroll
    for (int r = 0; r < 2; ++r) {
      afh[r] = *(const short8*)&Ah[r * 16 + m16][quad * 8];
      afl[r] = *(const short8*)&Al[r * 16 + m16][quad * 8];
    }
#pragma unroll
    for (int c = 0; c < 2; ++c) {
      const int col = w * 32 + c * 16 + m16;
      bfh[c] = *(const short8*)&Bh[col][quad * 8];
      bfl[c] = *(const short8*)&Bl[col][quad * 8];
    }
#pragma unroll
    for (int r = 0; r < 2; ++r)
#pragma unroll
      for (int c = 0; c < 2; ++c) {
        acc[r][c] = __builtin_amdgcn_mfma_f32_16x16x32_bf16(afh[r], bfh[c], acc[r][c], 0, 0, 0);
        acc[r][c] = __builtin_amdgcn_mfma_f32_16x16x32_bf16(afh[r], bfl[c], acc[r][c], 0, 0, 0);
        acc[r][c] = __builtin_amdgcn_mfma_f32_16x16x32_bf16(afl[r], bfh[c], acc[r][c], 0, 0, 0);
      }
  }

  float* outp = (g == 0) ? hk : (g == 1) ? hq : V;
  const float* bp = (g == 0) ? b1_k : (g == 1) ? b1_q : bv;
#pragma unroll
  for (int c = 0; c < 2; ++c) {
    const int colg = nb + w * 32 + c * 16 + m16;
    const float bias = bp[colg];
#pragma unroll
    for (int r = 0; r < 2; ++r)
#pragma unroll
      for (int j = 0; j < 4; ++j) {
        const int rowg = row0 + r * 16 + quad * 4 + j;
        float v = acc[r][c][j] + bias;
        if (g < 2) v = 0.5f * v * (1.0f + erff(v * 0.70710678f));
        outp[rowg * D + colg] = v;
      }
  }
}

// ---------------------------------------------------------------------------
// K2: layer-2 (phase & amp GEMMs [2048,256]@[256,64]) + phasor epilogue.
__global__ __launch_bounds__(256) void enc2_kernel(
    const float* __restrict__ x, const float* __restrict__ pos_k,
    const float* __restrict__ pos_q, const float* __restrict__ hk,
    const float* __restrict__ hq,
    const float* __restrict__ b2_k, const float* __restrict__ ba_k,
    const float* __restrict__ b2_q, const float* __restrict__ ba_q,
    const ushort* __restrict__ WT,
    float* __restrict__ kr, float* __restrict__ ki,
    float* __restrict__ qr, float* __restrict__ qi) {
  __shared__ __align__(16) ushort Ahh[16][40], Ahl[16][40], Axh[16][40], Axl[16][40];
  __shared__ __align__(16) ushort B2h[64][40], B2l[64][40], Bah[64][40], Bal[64][40];
  const int tid = threadIdx.x;
  const int e = blockIdx.x >> 7;
  const int r0g = (blockIdx.x & 127) * 16;
  const float* hsrc = e ? hq : hk;
  const float* pos = e ? pos_q : pos_k;
  const ushort* W2h = WT + WT2_OFF + (e ? 2 : 0) * 32768;
  const ushort* W2l = W2h + 16384;
  const ushort* Wah = WT + WT2_OFF + (e ? 3 : 1) * 32768;
  const ushort* Wal = Wah + 16384;
  const int w = tid >> 6, lane = tid & 63;
  const int m16 = lane & 15, quad = lane >> 4;

  float4v accP = {}, accA = {};
  for (int k0 = 0; k0 < 256; k0 += 32) {
    __syncthreads();
    {
      const int r = tid >> 4, kc = (tid & 15) * 2;
      const int row = r0g + r, l = row & (L - 1);
      const float2 hv = *(const float2*)&hsrc[row * D + k0 + kc];
      const float2 xv = *(const float2*)&x[row * D + k0 + kc];
      const float2 pv = *(const float2*)&pos[l * D + k0 + kc];
      const float a0 = xv.x + pv.x, a1 = xv.y + pv.y;
      ushort2 t;
      t.x = bf16_hi(hv.x); t.y = bf16_hi(hv.y); *(ushort2*)&Ahh[r][kc] = t;
      t.x = bf16_rne(hv.x - hi_f(hv.x)); t.y = bf16_rne(hv.y - hi_f(hv.y));
      *(ushort2*)&Ahl[r][kc] = t;
      t.x = bf16_hi(a0); t.y = bf16_hi(a1); *(ushort2*)&Axh[r][kc] = t;
      t.x = bf16_rne(a0 - hi_f(a0)); t.y = bf16_rne(a1 - hi_f(a1));
      *(ushort2*)&Axl[r][kc] = t;
    }
    {
      const int n = tid >> 2, chunk = tid & 3;
      const int ga = n * 256 + k0 + chunk * 8;
      *(uint4*)&B2h[n][chunk * 8] = *(const uint4*)&W2h[ga];
      *(uint4*)&B2l[n][chunk * 8] = *(const uint4*)&W2l[ga];
      *(uint4*)&Bah[n][chunk * 8] = *(const uint4*)&Wah[ga];
      *(uint4*)&Bal[n][chunk * 8] = *(const uint4*)&Wal[ga];
    }
    __syncthreads();

    const short8 ahh = *(const short8*)&Ahh[m16][quad * 8];
    const short8 ahl = *(const short8*)&Ahl[m16][quad * 8];
    const short8 axh = *(const short8*)&Axh[m16][quad * 8];
    const short8 axl = *(const short8*)&Axl[m16][quad * 8];
    const int col = w * 16 + m16;
    const short8 b2h = *(const short8*)&B2h[col][quad * 8];
    const short8 b2l = *(const short8*)&B2l[col][quad * 8];
    const short8 bah = *(const short8*)&Bah[col][quad * 8];
    const short8 bal = *(const short8*)&Bal[col][quad * 8];
    accP = __builtin_amdgcn_mfma_f32_16x16x32_bf16(ahh, b2h, accP, 0, 0, 0);
    accP = __builtin_amdgcn_mfma_f32_16x16x32_bf16(ahh, b2l, accP, 0, 0, 0);
    accP = __builtin_amdgcn_mfma_f32_16x16x32_bf16(ahl, b2h, accP, 0, 0, 0);
    accA = __builtin_amdgcn_mfma_f32_16x16x32_bf16(axh, bah, accA, 0, 0, 0);
    accA = __builtin_amdgcn_mfma_f32_16x16x32_bf16(axh, bal, accA, 0, 0, 0);
    accA = __builtin_amdgcn_mfma_f32_16x16x32_bf16(axl, bah, accA, 0, 0, 0);
  }

  float* pr = e ? qr : kr;
  float* pim = e ? qi : ki;
  const float* b2 = e ? b2_q : b2_k;
  const float* ba = e ? ba_q : ba_k;
  const int colk = w * 16 + m16;
  const float b2v = b2[colk], bav = ba[colk];
#pragma unroll
  for (int j = 0; j < 4; ++j) {
    const int row = r0g + quad * 4 + j;
    const float ph = tanhf(accP[j] + b2v) * 3.14159265358979f;
    const float av = accA[j] + bav;
    const float am = fmaxf(av, 0.0f) + log1pf(expf(-fabsf(av))) + 0.1f;
    pr[row * K + colk] = am * cosf(ph);
    pim[row * K + colk] = am * sinf(ph);
  }
}

// ---------------------------------------------------------------------------
// K3: per-chunk outer-product sums T[b][c][comp][k][d]. Grid (b,c,dc16)=512.
__global__ __launch_bounds__(256) void tbuild_kernel(
    const float* __restrict__ kr, const float* __restrict__ ki,
    const float* __restrict__ V, float* __restrict__ TM) {
  const int id = blockIdx.x;
  const int dc = id & 15, c = (id >> 4) & 15, b = id >> 8;
  const int tid = threadIdx.x;
  const int n0 = b * L + c * 64;
  const int d = dc * 16 + (tid & 15);
  const int kb = tid >> 4;

  __shared__ float krL[64][68], kiL[64][68];
  for (int e = tid; e < 1024; e += 256) {
    const int t = e >> 4, k4 = (e & 15) * 4;
    *(float4*)&krL[t][k4] = *(const float4*)&kr[(n0 + t) * K + k4];
    *(float4*)&kiL[t][k4] = *(const float4*)&ki[(n0 + t) * K + k4];
  }
  __syncthreads();

  float vcol[64];
#pragma unroll 8
  for (int t = 0; t < 64; ++t) vcol[t] = V[(n0 + t) * D + d];

  float ar[4] = {0.f, 0.f, 0.f, 0.f}, ai[4] = {0.f, 0.f, 0.f, 0.f};
#pragma unroll 4
  for (int t = 0; t < 64; ++t) {
    const float vt = vcol[t];
    const float4 k4r = *(const float4*)&krL[t][kb * 4];
    const float4 k4i = *(const float4*)&kiL[t][kb * 4];
    ar[0] += k4r.x * vt; ar[1] += k4r.y * vt; ar[2] += k4r.z * vt; ar[3] += k4r.w * vt;
    ai[0] += k4i.x * vt; ai[1] += k4i.y * vt; ai[2] += k4i.z * vt; ai[3] += k4i.w * vt;
  }

  const size_t base = (size_t)b * TM_BSTRIDE + (size_t)c * TM_CSTRIDE;
#pragma unroll
  for (int i = 0; i < 4; ++i) {
    const int k = kb * 4 + i;
    TM[base + (size_t)k * D + d] = ar[i];
    TM[base + (size_t)(K + k) * D + d] = ai[i];
  }
}

// ---------------------------------------------------------------------------
// K4: in-place exclusive prefix over c.
__global__ __launch_bounds__(256) void scan_kernel(float* __restrict__ TM) {
  const int col = blockIdx.x * 256 + threadIdx.x;
  const int d = col & 255;
  const int k = (col >> 8) & 63;
  const int comp = (col >> 14) & 1;
  const int b = col >> 15;
  size_t idx = (size_t)b * TM_BSTRIDE + (size_t)comp * (K * D) + (size_t)k * D + d;
  float run = 0.f;
#pragma unroll
  for (int c = 0; c < NC; ++c, idx += TM_CSTRIDE) {
    const float t = TM[idx];
    TM[idx] = run;
    run += t;
  }
}

// ---------------------------------------------------------------------------
// K5: fused per-chunk tail: S = Q.K^T (causal) -> ret = [Q|S].[M;V]
// -> /norm -> LN -> .wo + x + bo -> out. One block per (b, chunk) = 32 blocks.
// Uses ~152 KB LDS (gfx950 has 160 KB/CU); 1 block/CU by design.
__global__ __launch_bounds__(256) void out_fused_kernel(
    const float* __restrict__ qr, const float* __restrict__ qi,
    const float* __restrict__ kr, const float* __restrict__ ki,
    const float* __restrict__ V, const float* __restrict__ TM,
    const float* __restrict__ x, const float* __restrict__ ln_g,
    const float* __restrict__ ln_b, const ushort* __restrict__ WT,
    const float* __restrict__ bo, float* __restrict__ out) {
  __shared__ __align__(16) ushort A2h[64][200], A2l[64][200];  // 51.2 KB
  __shared__ __align__(16) float retL[64][260];                // 66.6 KB
  __shared__ __align__(16) char scratch[34816];                // 34 KB
  __shared__ float red1[64][4], red2[64][4], mu_s[64], rs_s[64];

  const int tid = threadIdx.x;
  const int b = blockIdx.x >> 4, c = blockIdx.x & 15;
  const int n0 = b * L + c * 64;
  const int w = tid >> 6, lane = tid & 63;
  const int m16 = lane & 15, quad = lane >> 4;

  ushort* Kh = (ushort*)scratch;        // [64][136]
  ushort* Kl = Kh + 64 * 136;

  // ---- Phase 0: stage Q -> A2[.,0:128], K -> Kh/Kl (hi/lo split) ----
#pragma unroll
  for (int j = 0; j < 8; ++j) {
    const int e = j * 256 + tid;
    const int row = e >> 5, c4 = e & 31;
    const int col0 = (c4 & 15) * 4;
    const int acol = (c4 < 16 ? 0 : 64) + col0;
    {
      const float* src = (c4 < 16) ? qr : qi;
      const float4 v = *(const float4*)&src[(n0 + row) * K + col0];
      ushort4 h4, l4;
      h4.x = bf16_hi(v.x); l4.x = bf16_rne(v.x - hi_f(v.x));
      h4.y = bf16_hi(v.y); l4.y = bf16_rne(v.y - hi_f(v.y));
      h4.z = bf16_hi(v.z); l4.z = bf16_rne(v.z - hi_f(v.z));
      h4.w = bf16_hi(v.w); l4.w = bf16_rne(v.w - hi_f(v.w));
      *(ushort4*)&A2h[row][acol] = h4;
      *(ushort4*)&A2l[row][acol] = l4;
    }
    {
      const float* src = (c4 < 16) ? kr : ki;
      const float4 v = *(const float4*)&src[(n0 + row) * K + col0];
      ushort4 h4, l4;
      h4.x = bf16_hi(v.x); l4.x = bf16_rne(v.x - hi_f(v.x));
      h4.y = bf16_hi(v.y); l4.y = bf16_rne(v.y - hi_f(v.y));
      h4.z = bf16_hi(v.z); l4.z = bf16_rne(v.z - hi_f(v.z));
      h4.w = bf16_hi(v.w); l4.w = bf16_rne(v.w - hi_f(v.w));
      *(ushort4*)&Kh[row * 136 + acol] = h4;
      *(ushort4*)&Kl[row * 136 + acol] = l4;
    }
  }
  __syncthreads();

  // ---- Phase 1: S = Q.K^T (64x64, inner 128), causal mask, -> A2[.,128:192]
  {
    float4v sc[4] = {};
#pragma unroll
    for (int kk = 0; kk < 128; kk += 32) {
      const short8 ah = *(const short8*)&A2h[w * 16 + m16][kk + quad * 8];
      const short8 al = *(const short8*)&A2l[w * 16 + m16][kk + quad * 8];
#pragma unroll
      for (int ct = 0; ct < 4; ++ct) {
        const short8 bh = *(const short8*)&Kh[(ct * 16 + m16) * 136 + kk + quad * 8];
        const short8 bl = *(const short8*)&Kl[(ct * 16 + m16) * 136 + kk + quad * 8];
        sc[ct] = __builtin_amdgcn_mfma_f32_16x16x32_bf16(ah, bh, sc[ct], 0, 0, 0);
        sc[ct] = __builtin_amdgcn_mfma_f32_16x16x32_bf16(ah, bl, sc[ct], 0, 0, 0);
        sc[ct] = __builtin_amdgcn_mfma_f32_16x16x32_bf16(al, bh, sc[ct], 0, 0, 0);
      }
    }
#pragma unroll
    for (int ct = 0; ct < 4; ++ct)
#pragma unroll
      for (int j = 0; j < 4; ++j) {
        const int row = w * 16 + quad * 4 + j;
        const int t = ct * 16 + m16;
        const float s = (t <= row) ? sc[ct][j] : 0.0f;
        A2h[row][128 + t] = bf16_hi(s);
        A2l[row][128 + t] = bf16_rne(s - hi_f(s));
      }
  }

  // ---- Phase 2: ret[64x256] = A2[64x192] . [M(128) ; V(64)][x256] ----
  const float* MT = TM + (size_t)b * TM_BSTRIDE + (size_t)c * TM_CSTRIDE;
  float* stage = (float*)scratch;       // [32][260]
  float4v r2[4][4] = {};
  for (int kk = 0; kk < 6; ++kk) {
    __syncthreads();
#pragma unroll
    for (int j = 0; j < 8; ++j) {
      const int e = j * 256 + tid;
      const int row = e >> 6, d4 = (e & 63) * 4;
      float4 v;
      if (kk < 4) v = *(const float4*)&MT[(size_t)(kk * 32 + row) * D + d4];
      else        v = *(const float4*)&V[(size_t)(n0 + (kk - 4) * 32 + row) * D + d4];
      *(float4*)&stage[row * 260 + d4] = v;
    }
    __syncthreads();

    short8 ah[4], al[4];
#pragma unroll
    for (int rt = 0; rt < 4; ++rt) {
      ah[rt] = *(const short8*)&A2h[rt * 16 + m16][kk * 32 + quad * 8];
      al[rt] = *(const short8*)&A2l[rt * 16 + m16][kk * 32 + quad * 8];
    }
#pragma unroll
    for (int ct = 0; ct < 4; ++ct) {
      const int n = w * 64 + ct * 16 + m16;
      short8 bh, bl;
#pragma unroll
      for (int j = 0; j < 8; ++j) {
        const float v = stage[(quad * 8 + j) * 260 + n];
        bh[j] = (short)bf16_hi(v);
        bl[j] = (short)bf16_rne(v - hi_f(v));
      }
#pragma unroll
      for (int rt = 0; rt < 4; ++rt) {
        r2[rt][ct] = __builtin_amdgcn_mfma_f32_16x16x32_bf16(ah[rt], bh, r2[rt][ct], 0, 0, 0);
        r2[rt][ct] = __builtin_amdgcn_mfma_f32_16x16x32_bf16(ah[rt], bl, r2[rt][ct], 0, 0, 0);
        r2[rt][ct] = __builtin_amdgcn_mfma_f32_16x16x32_bf16(al[rt], bh, r2[rt][ct], 0, 0, 0);
      }
    }
  }
  // write ret with /sqrt((l+1)*K)
#pragma unroll
  for (int rt = 0; rt < 4; ++rt)
#pragma unroll
    for (int ct = 0; ct < 4; ++ct)
#pragma unroll
      for (int j = 0; j < 4; ++j) {
        const int row = rt * 16 + quad * 4 + j;
        const int col = w * 64 + ct * 16 + m16;
        const float nrm = rsqrtf((float)(c * 64 + row + 1) * 64.0f);
        retL[row][col] = r2[rt][ct][j] * nrm;
      }
  __syncthreads();

  // ---- Phase 3: LayerNorm in LDS ----
  {
    const int row = tid >> 2, seg = tid & 3;
    float s = 0.f, s2 = 0.f;
    for (int i = 0; i < 64; ++i) {
      const float v = retL[row][seg * 64 + i];
      s += v; s2 += v * v;
    }
    red1[row][seg] = s; red2[row][seg] = s2;
  }
  __syncthreads();
  if (tid < 64) {
    const float s = red1[tid][0] + red1[tid][1] + red1[tid][2] + red1[tid][3];
    const float s2 = red2[tid][0] + red2[tid][1] + red2[tid][2] + red2[tid][3];
    const float mu = s * (1.0f / 256.0f);
    const float var = s2 * (1.0f / 256.0f) - mu * mu;
    mu_s[tid] = mu;
    rs_s[tid] = rsqrtf(var + 1e-5f);
  }
  __syncthreads();
  {
    const float g = ln_g[tid], bb = ln_b[tid];
    for (int row = 0; row < 64; ++row)
      retL[row][tid] = (retL[row][tid] - mu_s[row]) * rs_s[row] * g + bb;
  }

  // ---- Phase 4: out = x + rn . wo + bo (MFMA; wo planes from WT) ----
  ushort* Bwh = &A2h[0][0];             // reuse A2 region: [256][40]
  ushort* Bwl = &A2l[0][0];
  const ushort* Wh = WT + 3 * 131072;
  const ushort* Wl = Wh + 65536;
  float4v o2[4][4] = {};
  for (int kk = 0; kk < 8; ++kk) {
    __syncthreads();
#pragma unroll
    for (int cc = 0; cc < 4; ++cc) {
      *(uint4*)&Bwh[tid * 40 + cc * 8] = *(const uint4*)&Wh[tid * 256 + kk * 32 + cc * 8];
      *(uint4*)&Bwl[tid * 40 + cc * 8] = *(const uint4*)&Wl[tid * 256 + kk * 32 + cc * 8];
    }
    __syncthreads();

    short8 ah[4], al[4];
#pragma unroll
    for (int rt = 0; rt < 4; ++rt) {
      const float* rp = &retL[rt * 16 + m16][kk * 32 + quad * 8];
      const float4 u0 = *(const float4*)rp;
      const float4 u1 = *(const float4*)(rp + 4);
      const float vv[8] = {u0.x, u0.y, u0.z, u0.w, u1.x, u1.y, u1.z, u1.w};
#pragma unroll
      for (int j = 0; j < 8; ++j) {
        ah[rt][j] = (short)bf16_hi(vv[j]);
        al[rt][j] = (short)bf16_rne(vv[j] - hi_f(vv[j]));
      }
    }
#pragma unroll
    for (int ct = 0; ct < 4; ++ct) {
      const int col = w * 64 + ct * 16 + m16;
      const short8 bh = *(const short8*)&Bwh[col * 40 + quad * 8];
      const short8 bl = *(const short8*)&Bwl[col * 40 + quad * 8];
#pragma unroll
      for (int rt = 0; rt < 4; ++rt) {
        o2[rt][ct] = __builtin_amdgcn_mfma_f32_16x16x32_bf16(ah[rt], bh, o2[rt][ct], 0, 0, 0);
        o2[rt][ct] = __builtin_amdgcn_mfma_f32_16x16x32_bf16(ah[rt], bl, o2[rt][ct], 0, 0, 0);
        o2[rt][ct] = __builtin_amdgcn_mfma_f32_16x16x32_bf16(al[rt], bh, o2[rt][ct], 0, 0, 0);
      }
    }
  }

#pragma unroll
  for (int rt = 0; rt < 4; ++rt)
#pragma unroll
    for (int ct = 0; ct < 4; ++ct) {
      const int colg = w * 64 + ct * 16 + m16;
      const float bias = bo[colg];
#pragma unroll
      for (int j = 0; j < 4; ++j) {
        const int rowg = n0 + rt * 16 + quad * 4 + j;
        out[rowg * D + colg] = x[rowg * D + colg] + o2[rt][ct][j] + bias;
      }
    }
}

// ---------------------------------------------------------------------------
extern "C" void kernel_launch(void* const* d_in, const int* in_sizes, int n_in,
                              void* d_out, int out_size, void* d_ws, size_t ws_size,
                              hipStream_t stream) {
  (void)in_sizes; (void)n_in; (void)out_size; (void)ws_size;
  const float* x    = (const float*)d_in[0];
  const float* pos_k= (const float*)d_in[1];
  const float* w1_k = (const float*)d_in[2];
  const float* b1_k = (const float*)d_in[3];
  const float* w2_k = (const float*)d_in[4];
  const float* b2_k = (const float*)d_in[5];
  const float* wa_k = (const float*)d_in[6];
  const float* ba_k = (const float*)d_in[7];
  const float* pos_q= (const float*)d_in[8];
  const float* w1_q = (const float*)d_in[9];
  const float* b1_q = (const float*)d_in[10];
  const float* w2_q = (const float*)d_in[11];
  const float* b2_q = (const float*)d_in[12];
  const float* wa_q = (const float*)d_in[13];
  const float* ba_q = (const float*)d_in[14];
  const float* wv   = (const float*)d_in[15];
  const float* bv   = (const float*)d_in[16];
  const float* ln_g = (const float*)d_in[17];
  const float* ln_b = (const float*)d_in[18];
  const float* wo   = (const float*)d_in[19];
  const float* bo   = (const float*)d_in[20];

  float* ws = (float*)d_ws;
  float* kr = ws;                          // N*K
  float* ki = kr + (size_t)N * K;
  float* qr = ki + (size_t)N * K;
  float* qi = qr + (size_t)N * K;
  float* V  = qi + (size_t)N * K;          // N*D
  float* TM = V + (size_t)N * D;           // B*NC*2*K*D (4 MB)
  float* hk = TM + (size_t)B * NC * 2 * K * D;  // N*D
  float* hq = hk + (size_t)N * D;          // N*D
  ushort* WT = (ushort*)(hq + (size_t)N * D);   // 655360 ushorts (1.31 MB)

  prep_kernel<<<80, 256, 0, stream>>>(w1_k, w1_q, wv, wo,
                                      w2_k, wa_k, w2_q, wa_q, WT);
  enc1_kernel<<<384, 256, 0, stream>>>(x, pos_k, pos_q, b1_k, b1_q, bv, WT,
                                       hk, hq, V);
  enc2_kernel<<<256, 256, 0, stream>>>(x, pos_k, pos_q, hk, hq,
                                       b2_k, ba_k, b2_q, ba_q, WT,
                                       kr, ki, qr, qi);
  tbuild_kernel<<<B * NC * 16, 256, 0, stream>>>(kr, ki, V, TM);
  scan_kernel<<<(B * 2 * K * D) / 256, 256, 0, stream>>>(TM);
  out_fused_kernel<<<B * NC, 256, 0, stream>>>(qr, qi, kr, ki, V, TM, x,
                                               ln_g, ln_b, WT, bo,
                                               (float*)d_out);
}

// Round 11
// 160.853 us; speedup vs baseline: 1.2832x; 1.0903x over previous
//
#include <hip/hip_runtime.h>
#include <hip/hip_bf16.h>

typedef __attribute__((ext_vector_type(8))) short short8;
typedef __attribute__((ext_vector_type(4))) float float4v;

constexpr int B = 2, L = 1024, D = 256, K = 64;
constexpr int N = B * L;          // 2048 rows
constexpr int NC = L / 64;        // 16 chunks of 64 tokens

// WT arena (ushort units):
// big mats m in {w1_k, w1_q, wv, wo}: hi at m*131072, lo at +65536
// layer2 mats m in {w2_k, wa_k, w2_q, wa_q}: hi at WT2_OFF + m*32768, lo +16384
constexpr int WT2_OFF = 524288;

__device__ __forceinline__ ushort bf16_hi(float v) {
  return (ushort)(__float_as_uint(v) >> 16);
}
__device__ __forceinline__ float hi_f(float v) {
  return __uint_as_float(__float_as_uint(v) & 0xFFFF0000u);
}
__device__ __forceinline__ ushort bf16_rne(float v) {
  uint b = __float_as_uint(v);
  b += 0x7FFF + ((b >> 16) & 1);
  return (ushort)(b >> 16);
}

// ---------------------------------------------------------------------------
// K0: transpose + hi/lo split weights into WT arena (vector writes only).
__global__ __launch_bounds__(256) void prep_kernel(
    const float* __restrict__ w1_k, const float* __restrict__ w1_q,
    const float* __restrict__ wv, const float* __restrict__ wo,
    const float* __restrict__ w2_k, const float* __restrict__ wa_k,
    const float* __restrict__ w2_q, const float* __restrict__ wa_q,
    ushort* __restrict__ WT) {
  __shared__ float Lt[64][65];
  const int bi = blockIdx.x, tid = threadIdx.x;
  const float* src;
  int ncols, k0, n0;
  ushort* dhi;
  int losz;
  if (bi < 64) {
    const int m = bi >> 4, t = bi & 15;
    src = (m == 0) ? w1_k : (m == 1) ? w1_q : (m == 2) ? wv : wo;
    ncols = 256; k0 = (t >> 2) * 64; n0 = (t & 3) * 64;
    dhi = WT + m * 131072; losz = 65536;
  } else {
    const int m = (bi - 64) >> 2, kt = (bi - 64) & 3;
    src = (m == 0) ? w2_k : (m == 1) ? wa_k : (m == 2) ? w2_q : wa_q;
    ncols = 64; k0 = kt * 64; n0 = 0;
    dhi = WT + WT2_OFF + m * 32768; losz = 16384;
  }
  ushort* dlo = dhi + losz;
  for (int p = 0; p < 16; ++p) {
    const int kr = p * 4 + (tid >> 6), nc = tid & 63;
    Lt[kr][nc] = src[(k0 + kr) * ncols + n0 + nc];
  }
  __syncthreads();
  const int n = tid >> 2, kq = tid & 3;
  uint uh[8], ul[8];
  for (int i = 0; i < 8; ++i) {
    const float v0 = Lt[kq * 16 + 2 * i][n];
    const float v1 = Lt[kq * 16 + 2 * i + 1][n];
    uh[i] = (uint)bf16_hi(v0) | ((uint)bf16_hi(v1) << 16);
    ul[i] = (uint)bf16_rne(v0 - hi_f(v0)) | ((uint)bf16_rne(v1 - hi_f(v1)) << 16);
  }
  const int oidx = (n0 + n) * 256 + k0 + kq * 16;
  *(uint4*)&dhi[oidx] = make_uint4(uh[0], uh[1], uh[2], uh[3]);
  *(uint4*)&dhi[oidx + 8] = make_uint4(uh[4], uh[5], uh[6], uh[7]);
  *(uint4*)&dlo[oidx] = make_uint4(ul[0], ul[1], ul[2], ul[3]);
  *(uint4*)&dlo[oidx + 8] = make_uint4(ul[4], ul[5], ul[6], ul[7]);
}

// ---------------------------------------------------------------------------
// K1: layer-1 as 3 GEMMs [2048,256]@[256,256] via MFMA bf16x3.
__global__ __launch_bounds__(256) void enc1_kernel(
    const float* __restrict__ x, const float* __restrict__ pos_k,
    const float* __restrict__ pos_q,
    const float* __restrict__ b1_k, const float* __restrict__ b1_q,
    const float* __restrict__ bv, const ushort* __restrict__ WT,
    float* __restrict__ hk, float* __restrict__ hq, float* __restrict__ V) {
  __shared__ __align__(16) ushort Ah[32][40], Al[32][40];
  __shared__ __align__(16) ushort Bh[128][40], Bl[128][40];
  const int tid = threadIdx.x;
  const int g = blockIdx.x / 128;
  const int rem = blockIdx.x % 128;
  const int row0 = (rem >> 1) * 32, nb = (rem & 1) * 128;
  const float* pos = (g == 0) ? pos_k : (g == 1) ? pos_q : nullptr;
  const ushort* Wh = WT + g * 131072;
  const ushort* Wl = Wh + 65536;
  const int w = tid >> 6, lane = tid & 63;
  const int m16 = lane & 15, quad = lane >> 4;

  float4v acc[2][2] = {};

  for (int k0 = 0; k0 < 256; k0 += 32) {
    __syncthreads();
    {
      const int r = tid >> 3, kc = (tid & 7) * 4;
      const int row = row0 + r, l = row & (L - 1);
      float4 xv = *(const float4*)&x[row * D + k0 + kc];
      if (pos) {
        const float4 pv = *(const float4*)&pos[l * D + k0 + kc];
        xv.x += pv.x; xv.y += pv.y; xv.z += pv.z; xv.w += pv.w;
      }
      ushort4 h4, l4;
      h4.x = bf16_hi(xv.x); l4.x = bf16_rne(xv.x - hi_f(xv.x));
      h4.y = bf16_hi(xv.y); l4.y = bf16_rne(xv.y - hi_f(xv.y));
      h4.z = bf16_hi(xv.z); l4.z = bf16_rne(xv.z - hi_f(xv.z));
      h4.w = bf16_hi(xv.w); l4.w = bf16_rne(xv.w - hi_f(xv.w));
      *(ushort4*)&Ah[r][kc] = h4;
      *(ushort4*)&Al[r][kc] = l4;
    }
#pragma unroll
    for (int p = 0; p < 2; ++p) {
      const int n = (tid >> 2) + p * 64, chunk = tid & 3;
      const int ga = (nb + n) * 256 + k0 + chunk * 8;
      *(uint4*)&Bh[n][chunk * 8] = *(const uint4*)&Wh[ga];
      *(uint4*)&Bl[n][chunk * 8] = *(const uint4*)&Wl[ga];
    }
    __syncthreads();

    short8 afh[2], afl[2], bfh[2], bfl[2];
#pragma unroll
    for (int r = 0; r < 2; ++r) {
      afh[r] = *(const short8*)&Ah[r * 16 + m16][quad * 8];
      afl[r] = *(const short8*)&Al[r * 16 + m16][quad * 8];
    }
#pragma unroll
    for (int c = 0; c < 2; ++c) {
      const int col = w * 32 + c * 16 + m16;
      bfh[c] = *(const short8*)&Bh[col][quad * 8];
      bfl[c] = *(const short8*)&Bl[col][quad * 8];
    }
#pragma unroll
    for (int r = 0; r < 2; ++r)
#pragma unroll
      for (int c = 0; c < 2; ++c) {
        acc[r][c] = __builtin_amdgcn_mfma_f32_16x16x32_bf16(afh[r], bfh[c], acc[r][c], 0, 0, 0);
        acc[r][c] = __builtin_amdgcn_mfma_f32_16x16x32_bf16(afh[r], bfl[c], acc[r][c], 0, 0, 0);
        acc[r][c] = __builtin_amdgcn_mfma_f32_16x16x32_bf16(afl[r], bfh[c], acc[r][c], 0, 0, 0);
      }
  }

  float* outp = (g == 0) ? hk : (g == 1) ? hq : V;
  const float* bp = (g == 0) ? b1_k : (g == 1) ? b1_q : bv;
#pragma unroll
  for (int c = 0; c < 2; ++c) {
    const int colg = nb + w * 32 + c * 16 + m16;
    const float bias = bp[colg];
#pragma unroll
    for (int r = 0; r < 2; ++r)
#pragma unroll
      for (int j = 0; j < 4; ++j) {
        const int rowg = row0 + r * 16 + quad * 4 + j;
        float v = acc[r][c][j] + bias;
        if (g < 2) v = 0.5f * v * (1.0f + erff(v * 0.70710678f));
        outp[rowg * D + colg] = v;
      }
  }
}

// ---------------------------------------------------------------------------
// K2: layer-2 (phase & amp GEMMs [2048,256]@[256,64]) + phasor epilogue.
__global__ __launch_bounds__(256) void enc2_kernel(
    const float* __restrict__ x, const float* __restrict__ pos_k,
    const float* __restrict__ pos_q, const float* __restrict__ hk,
    const float* __restrict__ hq,
    const float* __restrict__ b2_k, const float* __restrict__ ba_k,
    const float* __restrict__ b2_q, const float* __restrict__ ba_q,
    const ushort* __restrict__ WT,
    float* __restrict__ kr, float* __restrict__ ki,
    float* __restrict__ qr, float* __restrict__ qi) {
  __shared__ __align__(16) ushort Ahh[16][40], Ahl[16][40], Axh[16][40], Axl[16][40];
  __shared__ __align__(16) ushort B2h[64][40], B2l[64][40], Bah[64][40], Bal[64][40];
  const int tid = threadIdx.x;
  const int e = blockIdx.x >> 7;
  const int r0g = (blockIdx.x & 127) * 16;
  const float* hsrc = e ? hq : hk;
  const float* pos = e ? pos_q : pos_k;
  const ushort* W2h = WT + WT2_OFF + (e ? 2 : 0) * 32768;
  const ushort* W2l = W2h + 16384;
  const ushort* Wah = WT + WT2_OFF + (e ? 3 : 1) * 32768;
  const ushort* Wal = Wah + 16384;
  const int w = tid >> 6, lane = tid & 63;
  const int m16 = lane & 15, quad = lane >> 4;

  float4v accP = {}, accA = {};
  for (int k0 = 0; k0 < 256; k0 += 32) {
    __syncthreads();
    {
      const int r = tid >> 4, kc = (tid & 15) * 2;
      const int row = r0g + r, l = row & (L - 1);
      const float2 hv = *(const float2*)&hsrc[row * D + k0 + kc];
      const float2 xv = *(const float2*)&x[row * D + k0 + kc];
      const float2 pv = *(const float2*)&pos[l * D + k0 + kc];
      const float a0 = xv.x + pv.x, a1 = xv.y + pv.y;
      ushort2 t;
      t.x = bf16_hi(hv.x); t.y = bf16_hi(hv.y); *(ushort2*)&Ahh[r][kc] = t;
      t.x = bf16_rne(hv.x - hi_f(hv.x)); t.y = bf16_rne(hv.y - hi_f(hv.y));
      *(ushort2*)&Ahl[r][kc] = t;
      t.x = bf16_hi(a0); t.y = bf16_hi(a1); *(ushort2*)&Axh[r][kc] = t;
      t.x = bf16_rne(a0 - hi_f(a0)); t.y = bf16_rne(a1 - hi_f(a1));
      *(ushort2*)&Axl[r][kc] = t;
    }
    {
      const int n = tid >> 2, chunk = tid & 3;
      const int ga = n * 256 + k0 + chunk * 8;
      *(uint4*)&B2h[n][chunk * 8] = *(const uint4*)&W2h[ga];
      *(uint4*)&B2l[n][chunk * 8] = *(const uint4*)&W2l[ga];
      *(uint4*)&Bah[n][chunk * 8] = *(const uint4*)&Wah[ga];
      *(uint4*)&Bal[n][chunk * 8] = *(const uint4*)&Wal[ga];
    }
    __syncthreads();

    const short8 ahh = *(const short8*)&Ahh[m16][quad * 8];
    const short8 ahl = *(const short8*)&Ahl[m16][quad * 8];
    const short8 axh = *(const short8*)&Axh[m16][quad * 8];
    const short8 axl = *(const short8*)&Axl[m16][quad * 8];
    const int col = w * 16 + m16;
    const short8 b2h = *(const short8*)&B2h[col][quad * 8];
    const short8 b2l = *(const short8*)&B2l[col][quad * 8];
    const short8 bah = *(const short8*)&Bah[col][quad * 8];
    const short8 bal = *(const short8*)&Bal[col][quad * 8];
    accP = __builtin_amdgcn_mfma_f32_16x16x32_bf16(ahh, b2h, accP, 0, 0, 0);
    accP = __builtin_amdgcn_mfma_f32_16x16x32_bf16(ahh, b2l, accP, 0, 0, 0);
    accP = __builtin_amdgcn_mfma_f32_16x16x32_bf16(ahl, b2h, accP, 0, 0, 0);
    accA = __builtin_amdgcn_mfma_f32_16x16x32_bf16(axh, bah, accA, 0, 0, 0);
    accA = __builtin_amdgcn_mfma_f32_16x16x32_bf16(axh, bal, accA, 0, 0, 0);
    accA = __builtin_amdgcn_mfma_f32_16x16x32_bf16(axl, bah, accA, 0, 0, 0);
  }

  float* pr = e ? qr : kr;
  float* pim = e ? qi : ki;
  const float* b2 = e ? b2_q : b2_k;
  const float* ba = e ? ba_q : ba_k;
  const int colk = w * 16 + m16;
  const float b2v = b2[colk], bav = ba[colk];
#pragma unroll
  for (int j = 0; j < 4; ++j) {
    const int row = r0g + quad * 4 + j;
    const float ph = tanhf(accP[j] + b2v) * 3.14159265358979f;
    const float av = accA[j] + bav;
    const float am = fmaxf(av, 0.0f) + log1pf(expf(-fabsf(av))) + 0.1f;
    pr[row * K + colk] = am * cosf(ph);
    pim[row * K + colk] = am * sinf(ph);
  }
}

// ---------------------------------------------------------------------------
// K3: per-chunk T + V^T into TMt[b][c][d][192] = [T_re(64)|T_im(64)|Vt(64)].
// Grid (b,c,dc16)=512. LDS-transposed, contiguous float4 output rows.
__global__ __launch_bounds__(256) void tbuild_kernel(
    const float* __restrict__ kr, const float* __restrict__ ki,
    const float* __restrict__ V, float* __restrict__ TMt) {
  const int id = blockIdx.x;
  const int dc = id & 15, c = (id >> 4) & 15, b = id >> 8;
  const int tid = threadIdx.x;
  const int n0 = b * L + c * 64;
  const int dl = tid & 15;
  const int d = dc * 16 + dl;
  const int kb = tid >> 4;

  __shared__ float krL[64][68], kiL[64][68];
  __shared__ float Tl[16][200];
  for (int e = tid; e < 1024; e += 256) {
    const int t = e >> 4, k4 = (e & 15) * 4;
    *(float4*)&krL[t][k4] = *(const float4*)&kr[(n0 + t) * K + k4];
    *(float4*)&kiL[t][k4] = *(const float4*)&ki[(n0 + t) * K + k4];
  }
  __syncthreads();

  float vcol[64];
#pragma unroll 8
  for (int t = 0; t < 64; ++t) vcol[t] = V[(n0 + t) * D + d];

  float ar[4] = {0.f, 0.f, 0.f, 0.f}, ai[4] = {0.f, 0.f, 0.f, 0.f};
#pragma unroll 4
  for (int t = 0; t < 64; ++t) {
    const float vt = vcol[t];
    const float4 k4r = *(const float4*)&krL[t][kb * 4];
    const float4 k4i = *(const float4*)&kiL[t][kb * 4];
    ar[0] += k4r.x * vt; ar[1] += k4r.y * vt; ar[2] += k4r.z * vt; ar[3] += k4r.w * vt;
    ai[0] += k4i.x * vt; ai[1] += k4i.y * vt; ai[2] += k4i.z * vt; ai[3] += k4i.w * vt;
  }

#pragma unroll
  for (int i = 0; i < 4; ++i) {
    Tl[dl][kb * 4 + i] = ar[i];
    Tl[dl][64 + kb * 4 + i] = ai[i];
  }
  if (kb == 0) {
#pragma unroll
    for (int j = 0; j < 16; ++j) Tl[dl][128 + j] = vcol[j];
  } else if (kb == 1) {
#pragma unroll
    for (int j = 0; j < 16; ++j) Tl[dl][144 + j] = vcol[16 + j];
  } else if (kb == 2) {
#pragma unroll
    for (int j = 0; j < 16; ++j) Tl[dl][160 + j] = vcol[32 + j];
  } else if (kb == 3) {
#pragma unroll
    for (int j = 0; j < 16; ++j) Tl[dl][176 + j] = vcol[48 + j];
  }
  __syncthreads();

  float* dst = &TMt[(((size_t)(b * 16 + c)) * 256 + dc * 16) * 192];
#pragma unroll
  for (int p = 0; p < 3; ++p) {
    const int e = p * 256 + tid;        // 0..767 = 16 rows x 48 float4
    const int row = e / 48, f4 = e % 48;
    *(float4*)&dst[(size_t)row * 192 + f4 * 4] = *(const float4*)&Tl[row][f4 * 4];
  }
}

// ---------------------------------------------------------------------------
// K4: in-place exclusive prefix over c (inner<128 only; Vt untouched).
__global__ __launch_bounds__(256) void scan_kernel(float* __restrict__ TMt) {
  const int col = blockIdx.x * 256 + threadIdx.x;   // 65536 columns
  const int b = col >> 15;
  const int d = (col >> 7) & 255;
  const int inner = col & 127;
  size_t idx = (((size_t)(b * 16)) * 256 + d) * 192 + inner;
  const size_t stride = (size_t)256 * 192;
  float run = 0.f;
#pragma unroll
  for (int c = 0; c < NC; ++c, idx += stride) {
    const float t = TMt[idx];
    TMt[idx] = run;
    run += t;
  }
}

// ---------------------------------------------------------------------------
// K5: ret slice via MFMA: S = Q.K^T (causal), ret = [Q|S].TMt_rows, scaled,
// plus per-slice LN partial sums. Grid (b,c,dc8) = 256 blocks.
__global__ __launch_bounds__(256) void ret_kernel(
    const float* __restrict__ qr, const float* __restrict__ qi,
    const float* __restrict__ kr, const float* __restrict__ ki,
    const float* __restrict__ TMt, float* __restrict__ ret,
    float* __restrict__ LNred) {
  __shared__ __align__(16) ushort Ah[64][200], Al[64][200];   // [Q(128)|S(64)]
  __shared__ __align__(16) ushort Kh[64][136], Kl[64][136];
  __shared__ __align__(16) ushort Bh[32][200], Bl[32][200];
  const int tid = threadIdx.x;
  const int dc = blockIdx.x & 7;
  const int c = (blockIdx.x >> 3) & 15;
  const int b = blockIdx.x >> 7;
  const int n0 = b * L + c * 64;
  const int cols0 = dc * 32;
  const int w = tid >> 6, lane = tid & 63;
  const int m16 = lane & 15, quad = lane >> 4;

  // Phase 0: stage Q -> Ah[.,0:128], K -> Kh (hi/lo)
#pragma unroll
  for (int j = 0; j < 8; ++j) {
    const int e = j * 256 + tid;
    const int row = e >> 5, c4 = e & 31;
    const int col0 = (c4 & 15) * 4;
    const int acol = (c4 < 16 ? 0 : 64) + col0;
    {
      const float* src = (c4 < 16) ? qr : qi;
      const float4 v = *(const float4*)&src[(n0 + row) * K + col0];
      ushort4 h4, l4;
      h4.x = bf16_hi(v.x); l4.x = bf16_rne(v.x - hi_f(v.x));
      h4.y = bf16_hi(v.y); l4.y = bf16_rne(v.y - hi_f(v.y));
      h4.z = bf16_hi(v.z); l4.z = bf16_rne(v.z - hi_f(v.z));
      h4.w = bf16_hi(v.w); l4.w = bf16_rne(v.w - hi_f(v.w));
      *(ushort4*)&Ah[row][acol] = h4;
      *(ushort4*)&Al[row][acol] = l4;
    }
    {
      const float* src = (c4 < 16) ? kr : ki;
      const float4 v = *(const float4*)&src[(n0 + row) * K + col0];
      ushort4 h4, l4;
      h4.x = bf16_hi(v.x); l4.x = bf16_rne(v.x - hi_f(v.x));
      h4.y = bf16_hi(v.y); l4.y = bf16_rne(v.y - hi_f(v.y));
      h4.z = bf16_hi(v.z); l4.z = bf16_rne(v.z - hi_f(v.z));
      h4.w = bf16_hi(v.w); l4.w = bf16_rne(v.w - hi_f(v.w));
      *(ushort4*)&Kh[row][acol] = h4;
      *(ushort4*)&Kl[row][acol] = l4;
    }
  }
  // Phase 2a can start staging B concurrently? No—keep simple, barrier.
  __syncthreads();

  // Phase 1: S = Q.K^T (64x64, inner 128), causal -> Ah[.,128:192]
  {
    float4v sc[4] = {};
#pragma unroll
    for (int kk = 0; kk < 128; kk += 32) {
      const short8 ah = *(const short8*)&Ah[w * 16 + m16][kk + quad * 8];
      const short8 al = *(const short8*)&Al[w * 16 + m16][kk + quad * 8];
#pragma unroll
      for (int ct = 0; ct < 4; ++ct) {
        const short8 bh = *(const short8*)&Kh[ct * 16 + m16][kk + quad * 8];
        const short8 bl = *(const short8*)&Kl[ct * 16 + m16][kk + quad * 8];
        sc[ct] = __builtin_amdgcn_mfma_f32_16x16x32_bf16(ah, bh, sc[ct], 0, 0, 0);
        sc[ct] = __builtin_amdgcn_mfma_f32_16x16x32_bf16(ah, bl, sc[ct], 0, 0, 0);
        sc[ct] = __builtin_amdgcn_mfma_f32_16x16x32_bf16(al, bh, sc[ct], 0, 0, 0);
      }
    }
#pragma unroll
    for (int ct = 0; ct < 4; ++ct)
#pragma unroll
      for (int j = 0; j < 4; ++j) {
        const int row = w * 16 + quad * 4 + j;
        const int t = ct * 16 + m16;
        const float s = (t <= row) ? sc[ct][j] : 0.0f;
        Ah[row][128 + t] = bf16_hi(s);
        Al[row][128 + t] = bf16_rne(s - hi_f(s));
      }
  }

  // Phase 2: stage B = TMt rows for cols0..cols0+31 (contiguous reads)
  {
    const float* src = &TMt[(((size_t)(b * 16 + c)) * 256 + cols0) * 192];
#pragma unroll
    for (int p = 0; p < 6; ++p) {
      const int e = p * 256 + tid;      // 0..1535 = 32 rows x 48 float4
      const int row = e / 48, f4 = e % 48;
      const float4 v = *(const float4*)&src[(size_t)row * 192 + f4 * 4];
      ushort4 h4, l4;
      h4.x = bf16_hi(v.x); l4.x = bf16_rne(v.x - hi_f(v.x));
      h4.y = bf16_hi(v.y); l4.y = bf16_rne(v.y - hi_f(v.y));
      h4.z = bf16_hi(v.z); l4.z = bf16_rne(v.z - hi_f(v.z));
      h4.w = bf16_hi(v.w); l4.w = bf16_rne(v.w - hi_f(v.w));
      *(ushort4*)&Bh[row][f4 * 4] = h4;
      *(ushort4*)&Bl[row][f4 * 4] = l4;
    }
  }
  __syncthreads();

  // Phase 3: ret slice = A[64x192] . B[32 cols][192], scale, LN partials
  {
    float4v r2[2] = {};
#pragma unroll
    for (int kk = 0; kk < 6; ++kk) {
      const short8 ah = *(const short8*)&Ah[w * 16 + m16][kk * 32 + quad * 8];
      const short8 al = *(const short8*)&Al[w * 16 + m16][kk * 32 + quad * 8];
#pragma unroll
      for (int ct = 0; ct < 2; ++ct) {
        const short8 bh = *(const short8*)&Bh[ct * 16 + m16][kk * 32 + quad * 8];
        const short8 bl = *(const short8*)&Bl[ct * 16 + m16][kk * 32 + quad * 8];
        r2[ct] = __builtin_amdgcn_mfma_f32_16x16x32_bf16(ah, bh, r2[ct], 0, 0, 0);
        r2[ct] = __builtin_amdgcn_mfma_f32_16x16x32_bf16(ah, bl, r2[ct], 0, 0, 0);
        r2[ct] = __builtin_amdgcn_mfma_f32_16x16x32_bf16(al, bh, r2[ct], 0, 0, 0);
      }
    }
#pragma unroll
    for (int j = 0; j < 4; ++j) {
      const int rowL = w * 16 + quad * 4 + j;
      const float nrm = rsqrtf((float)(c * 64 + rowL + 1) * 64.0f);
      float sj = 0.f, s2j = 0.f;
#pragma unroll
      for (int ct = 0; ct < 2; ++ct) {
        const float v = r2[ct][j] * nrm;
        ret[(size_t)(n0 + rowL) * D + cols0 + ct * 16 + m16] = v;
        sj += v; s2j += v * v;
      }
      for (int off = 1; off < 16; off <<= 1) {
        sj += __shfl_xor(sj, off, 64);
        s2j += __shfl_xor(s2j, off, 64);
      }
      if (m16 == 0) {
        LNred[(size_t)(n0 + rowL) * 16 + dc * 2 + 0] = sj;
        LNred[(size_t)(n0 + rowL) * 16 + dc * 2 + 1] = s2j;
      }
    }
  }
}

// ---------------------------------------------------------------------------
// K6: out = x + LN(ret).wo + bo via MFMA bf16x3, LN folded into A-staging.
// grid: row-tile32(64) x col-quarter64(4) = 256 blocks.
__global__ __launch_bounds__(256) void out2_kernel(
    const float* __restrict__ ret, const float* __restrict__ LNred,
    const float* __restrict__ x, const float* __restrict__ ln_g,
    const float* __restrict__ ln_b, const ushort* __restrict__ WT,
    const float* __restrict__ bo, float* __restrict__ out) {
  __shared__ __align__(16) ushort Ah[32][40], Al[32][40];
  __shared__ __align__(16) ushort Bh[64][40], Bl[64][40];
  __shared__ float mu_s[32], rs_s[32];
  const int tid = threadIdx.x;
  const int row0 = (blockIdx.x >> 2) * 32, nb = (blockIdx.x & 3) * 64;
  const ushort* Wh = WT + 3 * 131072;   // wo planes
  const ushort* Wl = Wh + 65536;
  const int w = tid >> 6, lane = tid & 63;
  const int m16 = lane & 15, quad = lane >> 4;

  if (tid < 32) {
    const int row = row0 + tid;
    float s = 0.f, s2 = 0.f;
#pragma unroll
    for (int i = 0; i < 8; ++i) {
      s += LNred[(size_t)row * 16 + i * 2 + 0];
      s2 += LNred[(size_t)row * 16 + i * 2 + 1];
    }
    const float mu = s * (1.0f / 256.0f);
    mu_s[tid] = mu;
    rs_s[tid] = rsqrtf(s2 * (1.0f / 256.0f) - mu * mu + 1e-5f);
  }

  float4v acc[2] = {};
  for (int k0 = 0; k0 < 256; k0 += 32) {
    __syncthreads();
    {  // stage A: rn = (ret - mu)*rs*g + b, hi/lo
      const int r = tid >> 3, kc = (tid & 7) * 4;
      const float4 v = *(const float4*)&ret[(size_t)(row0 + r) * D + k0 + kc];
      const float4 g4 = *(const float4*)&ln_g[k0 + kc];
      const float4 b4 = *(const float4*)&ln_b[k0 + kc];
      const float mu = mu_s[r], rs = rs_s[r];
      float a0 = (v.x - mu) * rs * g4.x + b4.x;
      float a1 = (v.y - mu) * rs * g4.y + b4.y;
      float a2 = (v.z - mu) * rs * g4.z + b4.z;
      float a3 = (v.w - mu) * rs * g4.w + b4.w;
      ushort4 h4, l4;
      h4.x = bf16_hi(a0); l4.x = bf16_rne(a0 - hi_f(a0));
      h4.y = bf16_hi(a1); l4.y = bf16_rne(a1 - hi_f(a1));
      h4.z = bf16_hi(a2); l4.z = bf16_rne(a2 - hi_f(a2));
      h4.w = bf16_hi(a3); l4.w = bf16_rne(a3 - hi_f(a3));
      *(ushort4*)&Ah[r][kc] = h4;
      *(ushort4*)&Al[r][kc] = l4;
    }
    {  // stage B from WT wo planes
      const int n = tid >> 2, chunk = tid & 3;
      const int ga = (nb + n) * 256 + k0 + chunk * 8;
      *(uint4*)&Bh[n][chunk * 8] = *(const uint4*)&Wh[ga];
      *(uint4*)&Bl[n][chunk * 8] = *(const uint4*)&Wl[ga];
    }
    __syncthreads();

    short8 afh[2], afl[2];
#pragma unroll
    for (int r = 0; r < 2; ++r) {
      afh[r] = *(const short8*)&Ah[r * 16 + m16][quad * 8];
      afl[r] = *(const short8*)&Al[r * 16 + m16][quad * 8];
    }
    const int col = w * 16 + m16;
    const short8 bfh = *(const short8*)&Bh[col][quad * 8];
    const short8 bfl = *(const short8*)&Bl[col][quad * 8];
#pragma unroll
    for (int r = 0; r < 2; ++r) {
      acc[r] = __builtin_amdgcn_mfma_f32_16x16x32_bf16(afh[r], bfh, acc[r], 0, 0, 0);
      acc[r] = __builtin_amdgcn_mfma_f32_16x16x32_bf16(afh[r], bfl, acc[r], 0, 0, 0);
      acc[r] = __builtin_amdgcn_mfma_f32_16x16x32_bf16(afl[r], bfh, acc[r], 0, 0, 0);
    }
  }

  const int colg = nb + w * 16 + m16;
  const float bias = bo[colg];
#pragma unroll
  for (int r = 0; r < 2; ++r)
#pragma unroll
    for (int j = 0; j < 4; ++j) {
      const int rowg = row0 + r * 16 + quad * 4 + j;
      out[rowg * D + colg] = x[rowg * D + colg] + acc[r][j] + bias;
    }
}

// ---------------------------------------------------------------------------
extern "C" void kernel_launch(void* const* d_in, const int* in_sizes, int n_in,
                              void* d_out, int out_size, void* d_ws, size_t ws_size,
                              hipStream_t stream) {
  (void)in_sizes; (void)n_in; (void)out_size; (void)ws_size;
  const float* x    = (const float*)d_in[0];
  const float* pos_k= (const float*)d_in[1];
  const float* w1_k = (const float*)d_in[2];
  const float* b1_k = (const float*)d_in[3];
  const float* w2_k = (const float*)d_in[4];
  const float* b2_k = (const float*)d_in[5];
  const float* wa_k = (const float*)d_in[6];
  const float* ba_k = (const float*)d_in[7];
  const float* pos_q= (const float*)d_in[8];
  const float* w1_q = (const float*)d_in[9];
  const float* b1_q = (const float*)d_in[10];
  const float* w2_q = (const float*)d_in[11];
  const float* b2_q = (const float*)d_in[12];
  const float* wa_q = (const float*)d_in[13];
  const float* ba_q = (const float*)d_in[14];
  const float* wv   = (const float*)d_in[15];
  const float* bv   = (const float*)d_in[16];
  const float* ln_g = (const float*)d_in[17];
  const float* ln_b = (const float*)d_in[18];
  const float* wo   = (const float*)d_in[19];
  const float* bo   = (const float*)d_in[20];

  float* ws = (float*)d_ws;
  float* kr = ws;                          // N*K
  float* ki = kr + (size_t)N * K;
  float* qr = ki + (size_t)N * K;
  float* qi = qr + (size_t)N * K;
  float* V  = qi + (size_t)N * K;          // N*D
  float* TMt = V + (size_t)N * D;          // B*NC*256*192 = 1.57M floats
  float* ret = TMt + (size_t)B * NC * 256 * 192;  // N*D
  float* LNred = ret + (size_t)N * D;      // N*16
  float* hk = LNred + (size_t)N * 16;      // N*D
  float* hq = hk + (size_t)N * D;          // N*D
  ushort* WT = (ushort*)(hq + (size_t)N * D);   // 655360 ushorts

  prep_kernel<<<80, 256, 0, stream>>>(w1_k, w1_q, wv, wo,
                                      w2_k, wa_k, w2_q, wa_q, WT);
  enc1_kernel<<<384, 256, 0, stream>>>(x, pos_k, pos_q, b1_k, b1_q, bv, WT,
                                       hk, hq, V);
  enc2_kernel<<<256, 256, 0, stream>>>(x, pos_k, pos_q, hk, hq,
                                       b2_k, ba_k, b2_q, ba_q, WT,
                                       kr, ki, qr, qi);
  tbuild_kernel<<<B * NC * 16, 256, 0, stream>>>(kr, ki, V, TMt);
  scan_kernel<<<256, 256, 0, stream>>>(TMt);
  ret_kernel<<<B * NC * 8, 256, 0, stream>>>(qr, qi, kr, ki, TMt, ret, LNred);
  out2_kernel<<<256, 256, 0, stream>>>(ret, LNred, x, ln_g, ln_b, WT, bo,
                                       (float*)d_out);
}

// Round 12
// 160.220 us; speedup vs baseline: 1.2883x; 1.0039x over previous
//
#include <hip/hip_runtime.h>
#include <hip/hip_bf16.h>

typedef __attribute__((ext_vector_type(8))) short short8;
typedef __attribute__((ext_vector_type(4))) float float4v;

constexpr int B = 2, L = 1024, D = 256, K = 64;
constexpr int N = B * L;          // 2048 rows
constexpr int NC = L / 64;        // 16 chunks of 64 tokens

// WT arena (ushort units):
// big mats m in {w1_k, w1_q, wv, wo}: hi at m*131072, lo at +65536
// layer2 mats m in {w2_k, wa_k, w2_q, wa_q}: hi at WT2_OFF + m*32768, lo +16384
constexpr int WT2_OFF = 524288;

__device__ __forceinline__ ushort bf16_hi(float v) {
  return (ushort)(__float_as_uint(v) >> 16);
}
__device__ __forceinline__ float hi_f(float v) {
  return __uint_as_float(__float_as_uint(v) & 0xFFFF0000u);
}
__device__ __forceinline__ ushort bf16_rne(float v) {
  uint b = __float_as_uint(v);
  b += 0x7FFF + ((b >> 16) & 1);
  return (ushort)(b >> 16);
}

// ---------------------------------------------------------------------------
// K0: transpose + hi/lo split weights into WT arena (vector writes only).
__global__ __launch_bounds__(256) void prep_kernel(
    const float* __restrict__ w1_k, const float* __restrict__ w1_q,
    const float* __restrict__ wv, const float* __restrict__ wo,
    const float* __restrict__ w2_k, const float* __restrict__ wa_k,
    const float* __restrict__ w2_q, const float* __restrict__ wa_q,
    ushort* __restrict__ WT) {
  __shared__ float Lt[64][65];
  const int bi = blockIdx.x, tid = threadIdx.x;
  const float* src;
  int ncols, k0, n0;
  ushort* dhi;
  int losz;
  if (bi < 64) {
    const int m = bi >> 4, t = bi & 15;
    src = (m == 0) ? w1_k : (m == 1) ? w1_q : (m == 2) ? wv : wo;
    ncols = 256; k0 = (t >> 2) * 64; n0 = (t & 3) * 64;
    dhi = WT + m * 131072; losz = 65536;
  } else {
    const int m = (bi - 64) >> 2, kt = (bi - 64) & 3;
    src = (m == 0) ? w2_k : (m == 1) ? wa_k : (m == 2) ? w2_q : wa_q;
    ncols = 64; k0 = kt * 64; n0 = 0;
    dhi = WT + WT2_OFF + m * 32768; losz = 16384;
  }
  ushort* dlo = dhi + losz;
  for (int p = 0; p < 16; ++p) {
    const int kr = p * 4 + (tid >> 6), nc = tid & 63;
    Lt[kr][nc] = src[(k0 + kr) * ncols + n0 + nc];
  }
  __syncthreads();
  const int n = tid >> 2, kq = tid & 3;
  uint uh[8], ul[8];
  for (int i = 0; i < 8; ++i) {
    const float v0 = Lt[kq * 16 + 2 * i][n];
    const float v1 = Lt[kq * 16 + 2 * i + 1][n];
    uh[i] = (uint)bf16_hi(v0) | ((uint)bf16_hi(v1) << 16);
    ul[i] = (uint)bf16_rne(v0 - hi_f(v0)) | ((uint)bf16_rne(v1 - hi_f(v1)) << 16);
  }
  const int oidx = (n0 + n) * 256 + k0 + kq * 16;
  *(uint4*)&dhi[oidx] = make_uint4(uh[0], uh[1], uh[2], uh[3]);
  *(uint4*)&dhi[oidx + 8] = make_uint4(uh[4], uh[5], uh[6], uh[7]);
  *(uint4*)&dlo[oidx] = make_uint4(ul[0], ul[1], ul[2], ul[3]);
  *(uint4*)&dlo[oidx + 8] = make_uint4(ul[4], ul[5], ul[6], ul[7]);
}

// ---------------------------------------------------------------------------
// K1: layer-1 as 3 GEMMs [2048,256]@[256,256] via MFMA bf16x3.
__global__ __launch_bounds__(256) void enc1_kernel(
    const float* __restrict__ x, const float* __restrict__ pos_k,
    const float* __restrict__ pos_q,
    const float* __restrict__ b1_k, const float* __restrict__ b1_q,
    const float* __restrict__ bv, const ushort* __restrict__ WT,
    float* __restrict__ hk, float* __restrict__ hq, float* __restrict__ V) {
  __shared__ __align__(16) ushort Ah[32][40], Al[32][40];
  __shared__ __align__(16) ushort Bh[128][40], Bl[128][40];
  const int tid = threadIdx.x;
  const int g = blockIdx.x / 128;
  const int rem = blockIdx.x % 128;
  const int row0 = (rem >> 1) * 32, nb = (rem & 1) * 128;
  const float* pos = (g == 0) ? pos_k : (g == 1) ? pos_q : nullptr;
  const ushort* Wh = WT + g * 131072;
  const ushort* Wl = Wh + 65536;
  const int w = tid >> 6, lane = tid & 63;
  const int m16 = lane & 15, quad = lane >> 4;

  float4v acc[2][2] = {};

  for (int k0 = 0; k0 < 256; k0 += 32) {
    __syncthreads();
    {
      const int r = tid >> 3, kc = (tid & 7) * 4;
      const int row = row0 + r, l = row & (L - 1);
      float4 xv = *(const float4*)&x[row * D + k0 + kc];
      if (pos) {
        const float4 pv = *(const float4*)&pos[l * D + k0 + kc];
        xv.x += pv.x; xv.y += pv.y; xv.z += pv.z; xv.w += pv.w;
      }
      ushort4 h4, l4;
      h4.x = bf16_hi(xv.x); l4.x = bf16_rne(xv.x - hi_f(xv.x));
      h4.y = bf16_hi(xv.y); l4.y = bf16_rne(xv.y - hi_f(xv.y));
      h4.z = bf16_hi(xv.z); l4.z = bf16_rne(xv.z - hi_f(xv.z));
      h4.w = bf16_hi(xv.w); l4.w = bf16_rne(xv.w - hi_f(xv.w));
      *(ushort4*)&Ah[r][kc] = h4;
      *(ushort4*)&Al[r][kc] = l4;
    }
#pragma unroll
    for (int p = 0; p < 2; ++p) {
      const int n = (tid >> 2) + p * 64, chunk = tid & 3;
      const int ga = (nb + n) * 256 + k0 + chunk * 8;
      *(uint4*)&Bh[n][chunk * 8] = *(const uint4*)&Wh[ga];
      *(uint4*)&Bl[n][chunk * 8] = *(const uint4*)&Wl[ga];
    }
    __syncthreads();

    short8 afh[2], afl[2], bfh[2], bfl[2];
#pragma unroll
    for (int r = 0; r < 2; ++r) {
      afh[r] = *(const short8*)&Ah[r * 16 + m16][quad * 8];
      afl[r] = *(const short8*)&Al[r * 16 + m16][quad * 8];
    }
#pragma unroll
    for (int c = 0; c < 2; ++c) {
      const int col = w * 32 + c * 16 + m16;
      bfh[c] = *(const short8*)&Bh[col][quad * 8];
      bfl[c] = *(const short8*)&Bl[col][quad * 8];
    }
#pragma unroll
    for (int r = 0; r < 2; ++r)
#pragma unroll
      for (int c = 0; c < 2; ++c) {
        acc[r][c] = __builtin_amdgcn_mfma_f32_16x16x32_bf16(afh[r], bfh[c], acc[r][c], 0, 0, 0);
        acc[r][c] = __builtin_amdgcn_mfma_f32_16x16x32_bf16(afh[r], bfl[c], acc[r][c], 0, 0, 0);
        acc[r][c] = __builtin_amdgcn_mfma_f32_16x16x32_bf16(afl[r], bfh[c], acc[r][c], 0, 0, 0);
      }
  }

  float* outp = (g == 0) ? hk : (g == 1) ? hq : V;
  const float* bp = (g == 0) ? b1_k : (g == 1) ? b1_q : bv;
#pragma unroll
  for (int c = 0; c < 2; ++c) {
    const int colg = nb + w * 32 + c * 16 + m16;
    const float bias = bp[colg];
#pragma unroll
    for (int r = 0; r < 2; ++r)
#pragma unroll
      for (int j = 0; j < 4; ++j) {
        const int rowg = row0 + r * 16 + quad * 4 + j;
        float v = acc[r][c][j] + bias;
        if (g < 2) v = 0.5f * v * (1.0f + erff(v * 0.70710678f));
        outp[rowg * D + colg] = v;
      }
  }
}

// ---------------------------------------------------------------------------
// K2: layer-2 (phase & amp GEMMs) + phasor epilogue. 256 blocks x 512 thr.
// 8 waves: (mat = w&1: phase|amp) x (ct = w>>1: 4 col tiles of 16).
__global__ __launch_bounds__(512) void enc2_kernel(
    const float* __restrict__ x, const float* __restrict__ pos_k,
    const float* __restrict__ pos_q, const float* __restrict__ hk,
    const float* __restrict__ hq,
    const float* __restrict__ b2_k, const float* __restrict__ ba_k,
    const float* __restrict__ b2_q, const float* __restrict__ ba_q,
    const ushort* __restrict__ WT,
    float* __restrict__ kr, float* __restrict__ ki,
    float* __restrict__ qr, float* __restrict__ qi) {
  __shared__ __align__(16) ushort Ahh[16][40], Ahl[16][40], Axh[16][40], Axl[16][40];
  __shared__ __align__(16) ushort B2h[64][40], B2l[64][40], Bah[64][40], Bal[64][40];
  __shared__ float phL[16][68], amL[16][68];
  const int tid = threadIdx.x;
  const int e = blockIdx.x >> 7;
  const int r0g = (blockIdx.x & 127) * 16;
  const float* hsrc = e ? hq : hk;
  const float* pos = e ? pos_q : pos_k;
  const ushort* W2h = WT + WT2_OFF + (e ? 2 : 0) * 32768;
  const ushort* W2l = W2h + 16384;
  const ushort* Wah = WT + WT2_OFF + (e ? 3 : 1) * 32768;
  const ushort* Wal = Wah + 16384;
  const int w = tid >> 6, lane = tid & 63;
  const int m16 = lane & 15, quad = lane >> 4;
  const int mat = w & 1, ct = w >> 1;

  float4v acc = {};
  for (int k0 = 0; k0 < 256; k0 += 32) {
    __syncthreads();
    {  // stage A: half 0 stages h, half 1 stages xa = x+pos (hi/lo, float2)
      const int half = tid >> 8;
      const int t2 = tid & 255;
      const int r = t2 >> 4, kc = (t2 & 15) * 2;
      const int row = r0g + r, l = row & (L - 1);
      if (half == 0) {
        const float2 hv = *(const float2*)&hsrc[row * D + k0 + kc];
        ushort2 h2, l2;
        h2.x = bf16_hi(hv.x); l2.x = bf16_rne(hv.x - hi_f(hv.x));
        h2.y = bf16_hi(hv.y); l2.y = bf16_rne(hv.y - hi_f(hv.y));
        *(ushort2*)&Ahh[r][kc] = h2;
        *(ushort2*)&Ahl[r][kc] = l2;
      } else {
        const float2 xv = *(const float2*)&x[row * D + k0 + kc];
        const float2 pv = *(const float2*)&pos[l * D + k0 + kc];
        const float a0 = xv.x + pv.x, a1 = xv.y + pv.y;
        ushort2 h2, l2;
        h2.x = bf16_hi(a0); l2.x = bf16_rne(a0 - hi_f(a0));
        h2.y = bf16_hi(a1); l2.y = bf16_rne(a1 - hi_f(a1));
        *(ushort2*)&Axh[r][kc] = h2;
        *(ushort2*)&Axl[r][kc] = l2;
      }
    }
    {  // stage B: 4 planes x 64 rows x 32 ushorts; 2 uint4 per thread
      const int sel = tid >> 7;         // 0: B2h, 1: B2l, 2: Bah, 3: Bal
      const int idx = tid & 127;
      const int n = idx >> 1, ch = (idx & 1) * 2;
      const int ga = n * 256 + k0 + ch * 8;
      const ushort* s = (sel == 0) ? W2h : (sel == 1) ? W2l : (sel == 2) ? Wah : Wal;
      ushort* dst = (sel == 0) ? &B2h[n][ch * 8] : (sel == 1) ? &B2l[n][ch * 8]
                  : (sel == 2) ? &Bah[n][ch * 8] : &Bal[n][ch * 8];
      *(uint4*)dst = *(const uint4*)&s[ga];
      *(uint4*)(dst + 8) = *(const uint4*)&s[ga + 8];
    }
    __syncthreads();

    const short8 ah = mat ? *(const short8*)&Axh[m16][quad * 8]
                          : *(const short8*)&Ahh[m16][quad * 8];
    const short8 al = mat ? *(const short8*)&Axl[m16][quad * 8]
                          : *(const short8*)&Ahl[m16][quad * 8];
    const int col = ct * 16 + m16;
    const short8 bh = mat ? *(const short8*)&Bah[col][quad * 8]
                          : *(const short8*)&B2h[col][quad * 8];
    const short8 bl = mat ? *(const short8*)&Bal[col][quad * 8]
                          : *(const short8*)&B2l[col][quad * 8];
    acc = __builtin_amdgcn_mfma_f32_16x16x32_bf16(ah, bh, acc, 0, 0, 0);
    acc = __builtin_amdgcn_mfma_f32_16x16x32_bf16(ah, bl, acc, 0, 0, 0);
    acc = __builtin_amdgcn_mfma_f32_16x16x32_bf16(al, bh, acc, 0, 0, 0);
  }

  // epilogue: phase waves -> phL, amp waves -> amL, then combined write
  {
    const int colk = ct * 16 + m16;
    if (mat == 0) {
      const float b2v = (e ? b2_q : b2_k)[colk];
#pragma unroll
      for (int j = 0; j < 4; ++j)
        phL[quad * 4 + j][colk] = tanhf(acc[j] + b2v) * 3.14159265358979f;
    } else {
      const float bav = (e ? ba_q : ba_k)[colk];
#pragma unroll
      for (int j = 0; j < 4; ++j) {
        const float av = acc[j] + bav;
        amL[quad * 4 + j][colk] = fmaxf(av, 0.0f) + log1pf(expf(-fabsf(av))) + 0.1f;
      }
    }
  }
  __syncthreads();
  {
    float* pr = e ? qr : kr;
    float* pim = e ? qi : ki;
#pragma unroll
    for (int p = 0; p < 2; ++p) {
      const int idx = p * 512 + tid;
      const int r = idx >> 6, ccol = idx & 63;
      const int row = r0g + r;
      const float a = amL[r][ccol], pph = phL[r][ccol];
      pr[row * K + ccol] = a * cosf(pph);
      pim[row * K + ccol] = a * sinf(pph);
    }
  }
}

// ---------------------------------------------------------------------------
// K3: per-chunk T + V^T into TMt[b][c][d][192] = [T_re(64)|T_im(64)|Vt(64)].
__global__ __launch_bounds__(256) void tbuild_kernel(
    const float* __restrict__ kr, const float* __restrict__ ki,
    const float* __restrict__ V, float* __restrict__ TMt) {
  const int id = blockIdx.x;
  const int dc = id & 15, c = (id >> 4) & 15, b = id >> 8;
  const int tid = threadIdx.x;
  const int n0 = b * L + c * 64;
  const int dl = tid & 15;
  const int d = dc * 16 + dl;
  const int kb = tid >> 4;

  __shared__ float krL[64][68], kiL[64][68];
  __shared__ float Tl[16][200];
  for (int e = tid; e < 1024; e += 256) {
    const int t = e >> 4, k4 = (e & 15) * 4;
    *(float4*)&krL[t][k4] = *(const float4*)&kr[(n0 + t) * K + k4];
    *(float4*)&kiL[t][k4] = *(const float4*)&ki[(n0 + t) * K + k4];
  }
  __syncthreads();

  float vcol[64];
#pragma unroll 8
  for (int t = 0; t < 64; ++t) vcol[t] = V[(n0 + t) * D + d];

  float ar[4] = {0.f, 0.f, 0.f, 0.f}, ai[4] = {0.f, 0.f, 0.f, 0.f};
#pragma unroll 4
  for (int t = 0; t < 64; ++t) {
    const float vt = vcol[t];
    const float4 k4r = *(const float4*)&krL[t][kb * 4];
    const float4 k4i = *(const float4*)&kiL[t][kb * 4];
    ar[0] += k4r.x * vt; ar[1] += k4r.y * vt; ar[2] += k4r.z * vt; ar[3] += k4r.w * vt;
    ai[0] += k4i.x * vt; ai[1] += k4i.y * vt; ai[2] += k4i.z * vt; ai[3] += k4i.w * vt;
  }

#pragma unroll
  for (int i = 0; i < 4; ++i) {
    Tl[dl][kb * 4 + i] = ar[i];
    Tl[dl][64 + kb * 4 + i] = ai[i];
  }
  if (kb == 0) {
#pragma unroll
    for (int j = 0; j < 16; ++j) Tl[dl][128 + j] = vcol[j];
  } else if (kb == 1) {
#pragma unroll
    for (int j = 0; j < 16; ++j) Tl[dl][144 + j] = vcol[16 + j];
  } else if (kb == 2) {
#pragma unroll
    for (int j = 0; j < 16; ++j) Tl[dl][160 + j] = vcol[32 + j];
  } else if (kb == 3) {
#pragma unroll
    for (int j = 0; j < 16; ++j) Tl[dl][176 + j] = vcol[48 + j];
  }
  __syncthreads();

  float* dst = &TMt[(((size_t)(b * 16 + c)) * 256 + dc * 16) * 192];
#pragma unroll
  for (int p = 0; p < 3; ++p) {
    const int e = p * 256 + tid;        // 0..767 = 16 rows x 48 float4
    const int row = e / 48, f4 = e % 48;
    *(float4*)&dst[(size_t)row * 192 + f4 * 4] = *(const float4*)&Tl[row][f4 * 4];
  }
}

// ---------------------------------------------------------------------------
// K4: in-place exclusive prefix over c (inner<128 only; Vt untouched).
__global__ __launch_bounds__(256) void scan_kernel(float* __restrict__ TMt) {
  const int col = blockIdx.x * 256 + threadIdx.x;   // 65536 columns
  const int b = col >> 15;
  const int d = (col >> 7) & 255;
  const int inner = col & 127;
  size_t idx = (((size_t)(b * 16)) * 256 + d) * 192 + inner;
  const size_t stride = (size_t)256 * 192;
  float run = 0.f;
#pragma unroll
  for (int c = 0; c < NC; ++c, idx += stride) {
    const float t = TMt[idx];
    TMt[idx] = run;
    run += t;
  }
}

// ---------------------------------------------------------------------------
// K5: ret slice via MFMA. Grid (b,c,dc8) = 256 blocks x 512 threads (8 waves).
__global__ __launch_bounds__(512) void ret_kernel(
    const float* __restrict__ qr, const float* __restrict__ qi,
    const float* __restrict__ kr, const float* __restrict__ ki,
    const float* __restrict__ TMt, float* __restrict__ ret,
    float* __restrict__ LNred) {
  __shared__ __align__(16) ushort Ah[64][200], Al[64][200];   // [Q(128)|S(64)]
  __shared__ __align__(16) ushort Kh[64][136], Kl[64][136];
  __shared__ __align__(16) ushort Bh[32][200], Bl[32][200];
  const int tid = threadIdx.x;
  const int dc = blockIdx.x & 7;
  const int c = (blockIdx.x >> 3) & 15;
  const int b = blockIdx.x >> 7;
  const int n0 = b * L + c * 64;
  const int cols0 = dc * 32;
  const int w = tid >> 6, lane = tid & 63;
  const int m16 = lane & 15, quad = lane >> 4;

  // Phase 0: stage Q -> Ah[.,0:128], K -> Kh (hi/lo)
#pragma unroll
  for (int j = 0; j < 4; ++j) {
    const int e = j * 512 + tid;
    const int row = e >> 5, c4 = e & 31;
    const int col0 = (c4 & 15) * 4;
    const int acol = (c4 < 16 ? 0 : 64) + col0;
    {
      const float* src = (c4 < 16) ? qr : qi;
      const float4 v = *(const float4*)&src[(n0 + row) * K + col0];
      ushort4 h4, l4;
      h4.x = bf16_hi(v.x); l4.x = bf16_rne(v.x - hi_f(v.x));
      h4.y = bf16_hi(v.y); l4.y = bf16_rne(v.y - hi_f(v.y));
      h4.z = bf16_hi(v.z); l4.z = bf16_rne(v.z - hi_f(v.z));
      h4.w = bf16_hi(v.w); l4.w = bf16_rne(v.w - hi_f(v.w));
      *(ushort4*)&Ah[row][acol] = h4;
      *(ushort4*)&Al[row][acol] = l4;
    }
    {
      const float* src = (c4 < 16) ? kr : ki;
      const float4 v = *(const float4*)&src[(n0 + row) * K + col0];
      ushort4 h4, l4;
      h4.x = bf16_hi(v.x); l4.x = bf16_rne(v.x - hi_f(v.x));
      h4.y = bf16_hi(v.y); l4.y = bf16_rne(v.y - hi_f(v.y));
      h4.z = bf16_hi(v.z); l4.z = bf16_rne(v.z - hi_f(v.z));
      h4.w = bf16_hi(v.w); l4.w = bf16_rne(v.w - hi_f(v.w));
      *(ushort4*)&Kh[row][acol] = h4;
      *(ushort4*)&Kl[row][acol] = l4;
    }
  }
  __syncthreads();

  // Phase 1: S = Q.K^T (64x64, inner 128), causal -> Ah[.,128:192]
  // 8 waves: (rt = w&3) x (ct pair = (w>>2)*2 + {0,1})
  {
    const int rt = w & 3;
    const int cp = (w >> 2) * 2;
    float4v sc[2] = {};
#pragma unroll
    for (int kk = 0; kk < 128; kk += 32) {
      const short8 ah = *(const short8*)&Ah[rt * 16 + m16][kk + quad * 8];
      const short8 al = *(const short8*)&Al[rt * 16 + m16][kk + quad * 8];
#pragma unroll
      for (int cc = 0; cc < 2; ++cc) {
        const int ct = cp + cc;
        const short8 bh = *(const short8*)&Kh[ct * 16 + m16][kk + quad * 8];
        const short8 bl = *(const short8*)&Kl[ct * 16 + m16][kk + quad * 8];
        sc[cc] = __builtin_amdgcn_mfma_f32_16x16x32_bf16(ah, bh, sc[cc], 0, 0, 0);
        sc[cc] = __builtin_amdgcn_mfma_f32_16x16x32_bf16(ah, bl, sc[cc], 0, 0, 0);
        sc[cc] = __builtin_amdgcn_mfma_f32_16x16x32_bf16(al, bh, sc[cc], 0, 0, 0);
      }
    }
#pragma unroll
    for (int cc = 0; cc < 2; ++cc)
#pragma unroll
      for (int j = 0; j < 4; ++j) {
        const int row = rt * 16 + quad * 4 + j;
        const int t = (cp + cc) * 16 + m16;
        const float s = (t <= row) ? sc[cc][j] : 0.0f;
        Ah[row][128 + t] = bf16_hi(s);
        Al[row][128 + t] = bf16_rne(s - hi_f(s));
      }
  }

  // Phase 2: stage B = TMt rows for cols0..cols0+31 (contiguous reads)
  {
    const float* src = &TMt[(((size_t)(b * 16 + c)) * 256 + cols0) * 192];
#pragma unroll
    for (int p = 0; p < 3; ++p) {
      const int e = p * 512 + tid;      // 0..1535 = 32 rows x 48 float4
      const int row = e / 48, f4 = e % 48;
      const float4 v = *(const float4*)&src[(size_t)row * 192 + f4 * 4];
      ushort4 h4, l4;
      h4.x = bf16_hi(v.x); l4.x = bf16_rne(v.x - hi_f(v.x));
      h4.y = bf16_hi(v.y); l4.y = bf16_rne(v.y - hi_f(v.y));
      h4.z = bf16_hi(v.z); l4.z = bf16_rne(v.z - hi_f(v.z));
      h4.w = bf16_hi(v.w); l4.w = bf16_rne(v.w - hi_f(v.w));
      *(ushort4*)&Bh[row][f4 * 4] = h4;
      *(ushort4*)&Bl[row][f4 * 4] = l4;
    }
  }
  __syncthreads();

  // Phase 3: ret slice = A[64x192] . B[32][192]; 8 waves = (rt=w&3) x (ct=w>>2)
  {
    const int rt = w & 3;
    const int ct = w >> 2;   // 0..1
    float4v r2 = {};
#pragma unroll
    for (int kk = 0; kk < 6; ++kk) {
      const short8 ah = *(const short8*)&Ah[rt * 16 + m16][kk * 32 + quad * 8];
      const short8 al = *(const short8*)&Al[rt * 16 + m16][kk * 32 + quad * 8];
      const short8 bh = *(const short8*)&Bh[ct * 16 + m16][kk * 32 + quad * 8];
      const short8 bl = *(const short8*)&Bl[ct * 16 + m16][kk * 32 + quad * 8];
      r2 = __builtin_amdgcn_mfma_f32_16x16x32_bf16(ah, bh, r2, 0, 0, 0);
      r2 = __builtin_amdgcn_mfma_f32_16x16x32_bf16(ah, bl, r2, 0, 0, 0);
      r2 = __builtin_amdgcn_mfma_f32_16x16x32_bf16(al, bh, r2, 0, 0, 0);
    }
#pragma unroll
    for (int j = 0; j < 4; ++j) {
      const int rowL = rt * 16 + quad * 4 + j;
      const float nrm = rsqrtf((float)(c * 64 + rowL + 1) * 64.0f);
      const float v = r2[j] * nrm;
      ret[(size_t)(n0 + rowL) * D + cols0 + ct * 16 + m16] = v;
      float sj = v, s2j = v * v;
      for (int off = 1; off < 16; off <<= 1) {
        sj += __shfl_xor(sj, off, 64);
        s2j += __shfl_xor(s2j, off, 64);
      }
      if (m16 == 0) {
        LNred[(size_t)(n0 + rowL) * 32 + (dc * 2 + ct) * 2 + 0] = sj;
        LNred[(size_t)(n0 + rowL) * 32 + (dc * 2 + ct) * 2 + 1] = s2j;
      }
    }
  }
}

// ---------------------------------------------------------------------------
// K6: out = x + LN(ret).wo + bo via MFMA bf16x3. 256 blocks x 512 threads.
// 8 waves = (rt = w&1) x (cq = w>>1).
__global__ __launch_bounds__(512) void out2_kernel(
    const float* __restrict__ ret, const float* __restrict__ LNred,
    const float* __restrict__ x, const float* __restrict__ ln_g,
    const float* __restrict__ ln_b, const ushort* __restrict__ WT,
    const float* __restrict__ bo, float* __restrict__ out) {
  __shared__ __align__(16) ushort Ah[32][40], Al[32][40];
  __shared__ __align__(16) ushort Bh[64][40], Bl[64][40];
  __shared__ float mu_s[32], rs_s[32];
  const int tid = threadIdx.x;
  const int row0 = (blockIdx.x >> 2) * 32, nb = (blockIdx.x & 3) * 64;
  const ushort* Wh = WT + 3 * 131072;   // wo planes
  const ushort* Wl = Wh + 65536;
  const int w = tid >> 6, lane = tid & 63;
  const int m16 = lane & 15, quad = lane >> 4;
  const int rt = w & 1, cq = w >> 1;

  if (tid < 32) {
    const int row = row0 + tid;
    float s = 0.f, s2 = 0.f;
#pragma unroll
    for (int i = 0; i < 16; ++i) {
      s += LNred[(size_t)row * 32 + i * 2 + 0];
      s2 += LNred[(size_t)row * 32 + i * 2 + 1];
    }
    const float mu = s * (1.0f / 256.0f);
    mu_s[tid] = mu;
    rs_s[tid] = rsqrtf(s2 * (1.0f / 256.0f) - mu * mu + 1e-5f);
  }

  float4v acc = {};
  for (int k0 = 0; k0 < 256; k0 += 32) {
    __syncthreads();
    {  // stage A: rn = (ret - mu)*rs*g + b, hi/lo (float2 per thread)
      const int r = tid >> 4, kc = (tid & 15) * 2;
      const float2 v = *(const float2*)&ret[(size_t)(row0 + r) * D + k0 + kc];
      const float2 g2 = *(const float2*)&ln_g[k0 + kc];
      const float2 b2 = *(const float2*)&ln_b[k0 + kc];
      const float mu = mu_s[r], rs = rs_s[r];
      const float a0 = (v.x - mu) * rs * g2.x + b2.x;
      const float a1 = (v.y - mu) * rs * g2.y + b2.y;
      ushort2 h2, l2;
      h2.x = bf16_hi(a0); l2.x = bf16_rne(a0 - hi_f(a0));
      h2.y = bf16_hi(a1); l2.y = bf16_rne(a1 - hi_f(a1));
      *(ushort2*)&Ah[r][kc] = h2;
      *(ushort2*)&Al[r][kc] = l2;
    }
    {  // stage B: hi plane by threads 0..255, lo by 256..511
      const int plane = tid >> 8;
      const int n = (tid >> 2) & 63, chunk = tid & 3;
      const int ga = (nb + n) * 256 + k0 + chunk * 8;
      if (plane == 0) *(uint4*)&Bh[n][chunk * 8] = *(const uint4*)&Wh[ga];
      else            *(uint4*)&Bl[n][chunk * 8] = *(const uint4*)&Wl[ga];
    }
    __syncthreads();

    const short8 afh = *(const short8*)&Ah[rt * 16 + m16][quad * 8];
    const short8 afl = *(const short8*)&Al[rt * 16 + m16][quad * 8];
    const int col = cq * 16 + m16;
    const short8 bfh = *(const short8*)&Bh[col][quad * 8];
    const short8 bfl = *(const short8*)&Bl[col][quad * 8];
    acc = __builtin_amdgcn_mfma_f32_16x16x32_bf16(afh, bfh, acc, 0, 0, 0);
    acc = __builtin_amdgcn_mfma_f32_16x16x32_bf16(afh, bfl, acc, 0, 0, 0);
    acc = __builtin_amdgcn_mfma_f32_16x16x32_bf16(afl, bfh, acc, 0, 0, 0);
  }

  const int colg = nb + cq * 16 + m16;
  const float bias = bo[colg];
#pragma unroll
  for (int j = 0; j < 4; ++j) {
    const int rowg = row0 + rt * 16 + quad * 4 + j;
    out[rowg * D + colg] = x[rowg * D + colg] + acc[j] + bias;
  }
}

// ---------------------------------------------------------------------------
extern "C" void kernel_launch(void* const* d_in, const int* in_sizes, int n_in,
                              void* d_out, int out_size, void* d_ws, size_t ws_size,
                              hipStream_t stream) {
  (void)in_sizes; (void)n_in; (void)out_size; (void)ws_size;
  const float* x    = (const float*)d_in[0];
  const float* pos_k= (const float*)d_in[1];
  const float* w1_k = (const float*)d_in[2];
  const float* b1_k = (const float*)d_in[3];
  const float* w2_k = (const float*)d_in[4];
  const float* b2_k = (const float*)d_in[5];
  const float* wa_k = (const float*)d_in[6];
  const float* ba_k = (const float*)d_in[7];
  const float* pos_q= (const float*)d_in[8];
  const float* w1_q = (const float*)d_in[9];
  const float* b1_q = (const float*)d_in[10];
  const float* w2_q = (const float*)d_in[11];
  const float* b2_q = (const float*)d_in[12];
  const float* wa_q = (const float*)d_in[13];
  const float* ba_q = (const float*)d_in[14];
  const float* wv   = (const float*)d_in[15];
  const float* bv   = (const float*)d_in[16];
  const float* ln_g = (const float*)d_in[17];
  const float* ln_b = (const float*)d_in[18];
  const float* wo   = (const float*)d_in[19];
  const float* bo   = (const float*)d_in[20];

  float* ws = (float*)d_ws;
  float* kr = ws;                          // N*K
  float* ki = kr + (size_t)N * K;
  float* qr = ki + (size_t)N * K;
  float* qi = qr + (size_t)N * K;
  float* V  = qi + (size_t)N * K;          // N*D
  float* TMt = V + (size_t)N * D;          // B*NC*256*192
  float* ret = TMt + (size_t)B * NC * 256 * 192;  // N*D
  float* LNred = ret + (size_t)N * D;      // N*32
  float* hk = LNred + (size_t)N * 32;      // N*D
  float* hq = hk + (size_t)N * D;          // N*D
  ushort* WT = (ushort*)(hq + (size_t)N * D);   // 655360 ushorts

  prep_kernel<<<80, 256, 0, stream>>>(w1_k, w1_q, wv, wo,
                                      w2_k, wa_k, w2_q, wa_q, WT);
  enc1_kernel<<<384, 256, 0, stream>>>(x, pos_k, pos_q, b1_k, b1_q, bv, WT,
                                       hk, hq, V);
  enc2_kernel<<<256, 512, 0, stream>>>(x, pos_k, pos_q, hk, hq,
                                       b2_k, ba_k, b2_q, ba_q, WT,
                                       kr, ki, qr, qi);
  tbuild_kernel<<<B * NC * 16, 256, 0, stream>>>(kr, ki, V, TMt);
  scan_kernel<<<256, 256, 0, stream>>>(TMt);
  ret_kernel<<<B * NC * 8, 512, 0, stream>>>(qr, qi, kr, ki, TMt, ret, LNred);
  out2_kernel<<<256, 512, 0, stream>>>(ret, LNred, x, ln_g, ln_b, WT, bo,
                                       (float*)d_out);
}

// Round 13
// 148.448 us; speedup vs baseline: 1.3905x; 1.0793x over previous
//
#include <hip/hip_runtime.h>
#include <hip/hip_bf16.h>

typedef __attribute__((ext_vector_type(8))) short short8;
typedef __attribute__((ext_vector_type(4))) float float4v;

constexpr int B = 2, L = 1024, D = 256, K = 64;
constexpr int N = B * L;          // 2048 rows
constexpr int NC = L / 64;        // 16 chunks of 64 tokens

// WT arena (ushort units):
// big mats m in {w1_k, w1_q, wv, wo}: hi at m*131072, lo at +65536
// layer2 mats m in {w2_k, wa_k, w2_q, wa_q}: hi at WT2_OFF + m*32768, lo +16384
constexpr int WT2_OFF = 524288;

__device__ __forceinline__ ushort bf16_hi(float v) {
  return (ushort)(__float_as_uint(v) >> 16);
}
__device__ __forceinline__ float hi_f(float v) {
  return __uint_as_float(__float_as_uint(v) & 0xFFFF0000u);
}
__device__ __forceinline__ ushort bf16_rne(float v) {
  uint b = __float_as_uint(v);
  b += 0x7FFF + ((b >> 16) & 1);
  return (ushort)(b >> 16);
}

// ---------------------------------------------------------------------------
// K0: transpose + hi/lo split weights into WT arena (vector writes only).
__global__ __launch_bounds__(256) void prep_kernel(
    const float* __restrict__ w1_k, const float* __restrict__ w1_q,
    const float* __restrict__ wv, const float* __restrict__ wo,
    const float* __restrict__ w2_k, const float* __restrict__ wa_k,
    const float* __restrict__ w2_q, const float* __restrict__ wa_q,
    ushort* __restrict__ WT) {
  __shared__ float Lt[64][65];
  const int bi = blockIdx.x, tid = threadIdx.x;
  const float* src;
  int ncols, k0, n0;
  ushort* dhi;
  int losz;
  if (bi < 64) {
    const int m = bi >> 4, t = bi & 15;
    src = (m == 0) ? w1_k : (m == 1) ? w1_q : (m == 2) ? wv : wo;
    ncols = 256; k0 = (t >> 2) * 64; n0 = (t & 3) * 64;
    dhi = WT + m * 131072; losz = 65536;
  } else {
    const int m = (bi - 64) >> 2, kt = (bi - 64) & 3;
    src = (m == 0) ? w2_k : (m == 1) ? wa_k : (m == 2) ? w2_q : wa_q;
    ncols = 64; k0 = kt * 64; n0 = 0;
    dhi = WT + WT2_OFF + m * 32768; losz = 16384;
  }
  ushort* dlo = dhi + losz;
  for (int p = 0; p < 16; ++p) {
    const int kr = p * 4 + (tid >> 6), nc = tid & 63;
    Lt[kr][nc] = src[(k0 + kr) * ncols + n0 + nc];
  }
  __syncthreads();
  const int n = tid >> 2, kq = tid & 3;
  uint uh[8], ul[8];
  for (int i = 0; i < 8; ++i) {
    const float v0 = Lt[kq * 16 + 2 * i][n];
    const float v1 = Lt[kq * 16 + 2 * i + 1][n];
    uh[i] = (uint)bf16_hi(v0) | ((uint)bf16_hi(v1) << 16);
    ul[i] = (uint)bf16_rne(v0 - hi_f(v0)) | ((uint)bf16_rne(v1 - hi_f(v1)) << 16);
  }
  const int oidx = (n0 + n) * 256 + k0 + kq * 16;
  *(uint4*)&dhi[oidx] = make_uint4(uh[0], uh[1], uh[2], uh[3]);
  *(uint4*)&dhi[oidx + 8] = make_uint4(uh[4], uh[5], uh[6], uh[7]);
  *(uint4*)&dlo[oidx] = make_uint4(ul[0], ul[1], ul[2], ul[3]);
  *(uint4*)&dlo[oidx + 8] = make_uint4(ul[4], ul[5], ul[6], ul[7]);
}

// ---------------------------------------------------------------------------
// K1: layer-1 as 3 GEMMs [2048,256]@[256,256] via MFMA bf16x3.
__global__ __launch_bounds__(256) void enc1_kernel(
    const float* __restrict__ x, const float* __restrict__ pos_k,
    const float* __restrict__ pos_q,
    const float* __restrict__ b1_k, const float* __restrict__ b1_q,
    const float* __restrict__ bv, const ushort* __restrict__ WT,
    float* __restrict__ hk, float* __restrict__ hq, float* __restrict__ V) {
  __shared__ __align__(16) ushort Ah[32][40], Al[32][40];
  __shared__ __align__(16) ushort Bh[128][40], Bl[128][40];
  const int tid = threadIdx.x;
  const int g = blockIdx.x / 128;
  const int rem = blockIdx.x % 128;
  const int row0 = (rem >> 1) * 32, nb = (rem & 1) * 128;
  const float* pos = (g == 0) ? pos_k : (g == 1) ? pos_q : nullptr;
  const ushort* Wh = WT + g * 131072;
  const ushort* Wl = Wh + 65536;
  const int w = tid >> 6, lane = tid & 63;
  const int m16 = lane & 15, quad = lane >> 4;

  float4v acc[2][2] = {};

  for (int k0 = 0; k0 < 256; k0 += 32) {
    __syncthreads();
    {
      const int r = tid >> 3, kc = (tid & 7) * 4;
      const int row = row0 + r, l = row & (L - 1);
      float4 xv = *(const float4*)&x[row * D + k0 + kc];
      if (pos) {
        const float4 pv = *(const float4*)&pos[l * D + k0 + kc];
        xv.x += pv.x; xv.y += pv.y; xv.z += pv.z; xv.w += pv.w;
      }
      ushort4 h4, l4;
      h4.x = bf16_hi(xv.x); l4.x = bf16_rne(xv.x - hi_f(xv.x));
      h4.y = bf16_hi(xv.y); l4.y = bf16_rne(xv.y - hi_f(xv.y));
      h4.z = bf16_hi(xv.z); l4.z = bf16_rne(xv.z - hi_f(xv.z));
      h4.w = bf16_hi(xv.w); l4.w = bf16_rne(xv.w - hi_f(xv.w));
      *(ushort4*)&Ah[r][kc] = h4;
      *(ushort4*)&Al[r][kc] = l4;
    }
#pragma unroll
    for (int p = 0; p < 2; ++p) {
      const int n = (tid >> 2) + p * 64, chunk = tid & 3;
      const int ga = (nb + n) * 256 + k0 + chunk * 8;
      *(uint4*)&Bh[n][chunk * 8] = *(const uint4*)&Wh[ga];
      *(uint4*)&Bl[n][chunk * 8] = *(const uint4*)&Wl[ga];
    }
    __syncthreads();

    short8 afh[2], afl[2], bfh[2], bfl[2];
#pragma unroll
    for (int r = 0; r < 2; ++r) {
      afh[r] = *(const short8*)&Ah[r * 16 + m16][quad * 8];
      afl[r] = *(const short8*)&Al[r * 16 + m16][quad * 8];
    }
#pragma unroll
    for (int c = 0; c < 2; ++c) {
      const int col = w * 32 + c * 16 + m16;
      bfh[c] = *(const short8*)&Bh[col][quad * 8];
      bfl[c] = *(const short8*)&Bl[col][quad * 8];
    }
#pragma unroll
    for (int r = 0; r < 2; ++r)
#pragma unroll
      for (int c = 0; c < 2; ++c) {
        acc[r][c] = __builtin_amdgcn_mfma_f32_16x16x32_bf16(afh[r], bfh[c], acc[r][c], 0, 0, 0);
        acc[r][c] = __builtin_amdgcn_mfma_f32_16x16x32_bf16(afh[r], bfl[c], acc[r][c], 0, 0, 0);
        acc[r][c] = __builtin_amdgcn_mfma_f32_16x16x32_bf16(afl[r], bfh[c], acc[r][c], 0, 0, 0);
      }
  }

  float* outp = (g == 0) ? hk : (g == 1) ? hq : V;
  const float* bp = (g == 0) ? b1_k : (g == 1) ? b1_q : bv;
#pragma unroll
  for (int c = 0; c < 2; ++c) {
    const int colg = nb + w * 32 + c * 16 + m16;
    const float bias = bp[colg];
#pragma unroll
    for (int r = 0; r < 2; ++r)
#pragma unroll
      for (int j = 0; j < 4; ++j) {
        const int rowg = row0 + r * 16 + quad * 4 + j;
        float v = acc[r][c][j] + bias;
        if (g < 2) v = 0.5f * v * (1.0f + erff(v * 0.70710678f));
        outp[rowg * D + colg] = v;
      }
  }
}

// ---------------------------------------------------------------------------
// K2: layer-2 (phase & amp GEMMs) + phasor epilogue. 256 blocks x 512 thr.
__global__ __launch_bounds__(512) void enc2_kernel(
    const float* __restrict__ x, const float* __restrict__ pos_k,
    const float* __restrict__ pos_q, const float* __restrict__ hk,
    const float* __restrict__ hq,
    const float* __restrict__ b2_k, const float* __restrict__ ba_k,
    const float* __restrict__ b2_q, const float* __restrict__ ba_q,
    const ushort* __restrict__ WT,
    float* __restrict__ kr, float* __restrict__ ki,
    float* __restrict__ qr, float* __restrict__ qi) {
  __shared__ __align__(16) ushort Ahh[16][40], Ahl[16][40], Axh[16][40], Axl[16][40];
  __shared__ __align__(16) ushort B2h[64][40], B2l[64][40], Bah[64][40], Bal[64][40];
  __shared__ float phL[16][68], amL[16][68];
  const int tid = threadIdx.x;
  const int e = blockIdx.x >> 7;
  const int r0g = (blockIdx.x & 127) * 16;
  const float* hsrc = e ? hq : hk;
  const float* pos = e ? pos_q : pos_k;
  const ushort* W2h = WT + WT2_OFF + (e ? 2 : 0) * 32768;
  const ushort* W2l = W2h + 16384;
  const ushort* Wah = WT + WT2_OFF + (e ? 3 : 1) * 32768;
  const ushort* Wal = Wah + 16384;
  const int w = tid >> 6, lane = tid & 63;
  const int m16 = lane & 15, quad = lane >> 4;
  const int mat = w & 1, ct = w >> 1;

  float4v acc = {};
  for (int k0 = 0; k0 < 256; k0 += 32) {
    __syncthreads();
    {
      const int half = tid >> 8;
      const int t2 = tid & 255;
      const int r = t2 >> 4, kc = (t2 & 15) * 2;
      const int row = r0g + r, l = row & (L - 1);
      if (half == 0) {
        const float2 hv = *(const float2*)&hsrc[row * D + k0 + kc];
        ushort2 h2, l2;
        h2.x = bf16_hi(hv.x); l2.x = bf16_rne(hv.x - hi_f(hv.x));
        h2.y = bf16_hi(hv.y); l2.y = bf16_rne(hv.y - hi_f(hv.y));
        *(ushort2*)&Ahh[r][kc] = h2;
        *(ushort2*)&Ahl[r][kc] = l2;
      } else {
        const float2 xv = *(const float2*)&x[row * D + k0 + kc];
        const float2 pv = *(const float2*)&pos[l * D + k0 + kc];
        const float a0 = xv.x + pv.x, a1 = xv.y + pv.y;
        ushort2 h2, l2;
        h2.x = bf16_hi(a0); l2.x = bf16_rne(a0 - hi_f(a0));
        h2.y = bf16_hi(a1); l2.y = bf16_rne(a1 - hi_f(a1));
        *(ushort2*)&Axh[r][kc] = h2;
        *(ushort2*)&Axl[r][kc] = l2;
      }
    }
    {
      const int sel = tid >> 7;
      const int idx = tid & 127;
      const int n = idx >> 1, ch = (idx & 1) * 2;
      const int ga = n * 256 + k0 + ch * 8;
      const ushort* s = (sel == 0) ? W2h : (sel == 1) ? W2l : (sel == 2) ? Wah : Wal;
      ushort* dst = (sel == 0) ? &B2h[n][ch * 8] : (sel == 1) ? &B2l[n][ch * 8]
                  : (sel == 2) ? &Bah[n][ch * 8] : &Bal[n][ch * 8];
      *(uint4*)dst = *(const uint4*)&s[ga];
      *(uint4*)(dst + 8) = *(const uint4*)&s[ga + 8];
    }
    __syncthreads();

    const short8 ah = mat ? *(const short8*)&Axh[m16][quad * 8]
                          : *(const short8*)&Ahh[m16][quad * 8];
    const short8 al = mat ? *(const short8*)&Axl[m16][quad * 8]
                          : *(const short8*)&Ahl[m16][quad * 8];
    const int col = ct * 16 + m16;
    const short8 bh = mat ? *(const short8*)&Bah[col][quad * 8]
                          : *(const short8*)&B2h[col][quad * 8];
    const short8 bl = mat ? *(const short8*)&Bal[col][quad * 8]
                          : *(const short8*)&B2l[col][quad * 8];
    acc = __builtin_amdgcn_mfma_f32_16x16x32_bf16(ah, bh, acc, 0, 0, 0);
    acc = __builtin_amdgcn_mfma_f32_16x16x32_bf16(ah, bl, acc, 0, 0, 0);
    acc = __builtin_amdgcn_mfma_f32_16x16x32_bf16(al, bh, acc, 0, 0, 0);
  }

  {
    const int colk = ct * 16 + m16;
    if (mat == 0) {
      const float b2v = (e ? b2_q : b2_k)[colk];
#pragma unroll
      for (int j = 0; j < 4; ++j)
        phL[quad * 4 + j][colk] = tanhf(acc[j] + b2v) * 3.14159265358979f;
    } else {
      const float bav = (e ? ba_q : ba_k)[colk];
#pragma unroll
      for (int j = 0; j < 4; ++j) {
        const float av = acc[j] + bav;
        amL[quad * 4 + j][colk] = fmaxf(av, 0.0f) + log1pf(expf(-fabsf(av))) + 0.1f;
      }
    }
  }
  __syncthreads();
  {
    float* pr = e ? qr : kr;
    float* pim = e ? qi : ki;
#pragma unroll
    for (int p = 0; p < 2; ++p) {
      const int idx = p * 512 + tid;
      const int r = idx >> 6, ccol = idx & 63;
      const int row = r0g + r;
      const float a = amL[r][ccol], pph = phL[r][ccol];
      pr[row * K + ccol] = a * cosf(pph);
      pim[row * K + ccol] = a * sinf(pph);
    }
  }
}

// ---------------------------------------------------------------------------
// K3: per-chunk T + V^T into TMt[b][c][d][192] = [T_re(64)|T_im(64)|Vt(64)].
// V staged once in LDS (no 16x redundant loads), Tl padded to 204.
__global__ __launch_bounds__(256) void tbuild_kernel(
    const float* __restrict__ kr, const float* __restrict__ ki,
    const float* __restrict__ V, float* __restrict__ TMt) {
  const int id = blockIdx.x;
  const int dc = id & 15, c = (id >> 4) & 15, b = id >> 8;
  const int tid = threadIdx.x;
  const int n0 = b * L + c * 64;
  const int dl = tid & 15;
  const int kb = tid >> 4;

  __shared__ float krL[64][68], kiL[64][68];
  __shared__ float VL[64][20];
  __shared__ float Tl[16][204];
  for (int e = tid; e < 1024; e += 256) {
    const int t = e >> 4, k4 = (e & 15) * 4;
    *(float4*)&krL[t][k4] = *(const float4*)&kr[(n0 + t) * K + k4];
    *(float4*)&kiL[t][k4] = *(const float4*)&ki[(n0 + t) * K + k4];
  }
  {  // stage V slice [64 t][16 d] once, coalesced float4
    const int t = tid >> 2, f = (tid & 3) * 4;
    *(float4*)&VL[t][f] = *(const float4*)&V[(n0 + t) * D + dc * 16 + f];
  }
  __syncthreads();

  // fill Vt part of Tl from VL (transpose in LDS)
  {
    const int t0 = (tid >> 4) * 4;
#pragma unroll
    for (int i = 0; i < 4; ++i) Tl[dl][128 + t0 + i] = VL[t0 + i][dl];
  }

  float ar[4] = {0.f, 0.f, 0.f, 0.f}, ai[4] = {0.f, 0.f, 0.f, 0.f};
#pragma unroll 4
  for (int t = 0; t < 64; ++t) {
    const float vt = VL[t][dl];
    const float4 k4r = *(const float4*)&krL[t][kb * 4];
    const float4 k4i = *(const float4*)&kiL[t][kb * 4];
    ar[0] += k4r.x * vt; ar[1] += k4r.y * vt; ar[2] += k4r.z * vt; ar[3] += k4r.w * vt;
    ai[0] += k4i.x * vt; ai[1] += k4i.y * vt; ai[2] += k4i.z * vt; ai[3] += k4i.w * vt;
  }

#pragma unroll
  for (int i = 0; i < 4; ++i) {
    Tl[dl][kb * 4 + i] = ar[i];
    Tl[dl][64 + kb * 4 + i] = ai[i];
  }
  __syncthreads();

  float* dst = &TMt[(((size_t)(b * 16 + c)) * 256 + dc * 16) * 192];
#pragma unroll
  for (int p = 0; p < 3; ++p) {
    const int e = p * 256 + tid;        // 0..767 = 16 rows x 48 float4
    const int row = e / 48, f4 = e % 48;
    *(float4*)&dst[(size_t)row * 192 + f4 * 4] = *(const float4*)&Tl[row][f4 * 4];
  }
}

// ---------------------------------------------------------------------------
// K4: ret slice via MFMA, with the chunk prefix (scan) folded in:
// M_c = sum_{c'<c} T_{c'} accumulated in registers during B staging.
// Grid (b,c,dc8) = 256 blocks x 512 threads (8 waves).
__global__ __launch_bounds__(512) void ret_kernel(
    const float* __restrict__ qr, const float* __restrict__ qi,
    const float* __restrict__ kr, const float* __restrict__ ki,
    const float* __restrict__ TMt, float* __restrict__ ret,
    float* __restrict__ LNred) {
  __shared__ __align__(16) ushort Ah[64][200], Al[64][200];   // [Q(128)|S(64)]
  __shared__ __align__(16) ushort Kh[64][136], Kl[64][136];
  __shared__ __align__(16) ushort Bh[32][200], Bl[32][200];
  const int tid = threadIdx.x;
  const int dc = blockIdx.x & 7;
  const int c = (blockIdx.x >> 3) & 15;
  const int b = blockIdx.x >> 7;
  const int n0 = b * L + c * 64;
  const int cols0 = dc * 32;
  const int w = tid >> 6, lane = tid & 63;
  const int m16 = lane & 15, quad = lane >> 4;

  // Phase 0: stage Q -> Ah[.,0:128], K -> Kh (hi/lo)
#pragma unroll
  for (int j = 0; j < 4; ++j) {
    const int e = j * 512 + tid;
    const int row = e >> 5, c4 = e & 31;
    const int col0 = (c4 & 15) * 4;
    const int acol = (c4 < 16 ? 0 : 64) + col0;
    {
      const float* src = (c4 < 16) ? qr : qi;
      const float4 v = *(const float4*)&src[(n0 + row) * K + col0];
      ushort4 h4, l4;
      h4.x = bf16_hi(v.x); l4.x = bf16_rne(v.x - hi_f(v.x));
      h4.y = bf16_hi(v.y); l4.y = bf16_rne(v.y - hi_f(v.y));
      h4.z = bf16_hi(v.z); l4.z = bf16_rne(v.z - hi_f(v.z));
      h4.w = bf16_hi(v.w); l4.w = bf16_rne(v.w - hi_f(v.w));
      *(ushort4*)&Ah[row][acol] = h4;
      *(ushort4*)&Al[row][acol] = l4;
    }
    {
      const float* src = (c4 < 16) ? kr : ki;
      const float4 v = *(const float4*)&src[(n0 + row) * K + col0];
      ushort4 h4, l4;
      h4.x = bf16_hi(v.x); l4.x = bf16_rne(v.x - hi_f(v.x));
      h4.y = bf16_hi(v.y); l4.y = bf16_rne(v.y - hi_f(v.y));
      h4.z = bf16_hi(v.z); l4.z = bf16_rne(v.z - hi_f(v.z));
      h4.w = bf16_hi(v.w); l4.w = bf16_rne(v.w - hi_f(v.w));
      *(ushort4*)&Kh[row][acol] = h4;
      *(ushort4*)&Kl[row][acol] = l4;
    }
  }

  // Prefix accumulation (registers; independent of LDS staging above):
  // thread owns 8 floats of the 32x128 M-block: row = tid>>4, in0 = (tid&15)*8
  float4 mac0 = {}, mac1 = {};
  {
    const int prow = tid >> 4, in0 = (tid & 15) * 8;
    const float* base = &TMt[(size_t)(b * 16) * 256 * 192 +
                             (size_t)(cols0 + prow) * 192 + in0];
    for (int cp = 0; cp < c; ++cp) {
      const float* p = base + (size_t)cp * 256 * 192;
      const float4 v0 = *(const float4*)p;
      const float4 v1 = *(const float4*)(p + 4);
      mac0.x += v0.x; mac0.y += v0.y; mac0.z += v0.z; mac0.w += v0.w;
      mac1.x += v1.x; mac1.y += v1.y; mac1.z += v1.z; mac1.w += v1.w;
    }
  }
  __syncthreads();

  // Phase 1: S = Q.K^T (64x64, inner 128), causal -> Ah[.,128:192]
  {
    const int rt = w & 3;
    const int cp = (w >> 2) * 2;
    float4v sc[2] = {};
#pragma unroll
    for (int kk = 0; kk < 128; kk += 32) {
      const short8 ah = *(const short8*)&Ah[rt * 16 + m16][kk + quad * 8];
      const short8 al = *(const short8*)&Al[rt * 16 + m16][kk + quad * 8];
#pragma unroll
      for (int cc = 0; cc < 2; ++cc) {
        const int ct = cp + cc;
        const short8 bh = *(const short8*)&Kh[ct * 16 + m16][kk + quad * 8];
        const short8 bl = *(const short8*)&Kl[ct * 16 + m16][kk + quad * 8];
        sc[cc] = __builtin_amdgcn_mfma_f32_16x16x32_bf16(ah, bh, sc[cc], 0, 0, 0);
        sc[cc] = __builtin_amdgcn_mfma_f32_16x16x32_bf16(ah, bl, sc[cc], 0, 0, 0);
        sc[cc] = __builtin_amdgcn_mfma_f32_16x16x32_bf16(al, bh, sc[cc], 0, 0, 0);
      }
    }
#pragma unroll
    for (int cc = 0; cc < 2; ++cc)
#pragma unroll
      for (int j = 0; j < 4; ++j) {
        const int row = rt * 16 + quad * 4 + j;
        const int t = (cp + cc) * 16 + m16;
        const float s = (t <= row) ? sc[cc][j] : 0.0f;
        Ah[row][128 + t] = bf16_hi(s);
        Al[row][128 + t] = bf16_rne(s - hi_f(s));
      }
  }

  // Phase 2: stage B = [M_c (from regs) | Vt_c (from TMt)] hi/lo
  {
    const int prow = tid >> 4, in0 = (tid & 15) * 8;
    ushort4 h4, l4;
    h4.x = bf16_hi(mac0.x); l4.x = bf16_rne(mac0.x - hi_f(mac0.x));
    h4.y = bf16_hi(mac0.y); l4.y = bf16_rne(mac0.y - hi_f(mac0.y));
    h4.z = bf16_hi(mac0.z); l4.z = bf16_rne(mac0.z - hi_f(mac0.z));
    h4.w = bf16_hi(mac0.w); l4.w = bf16_rne(mac0.w - hi_f(mac0.w));
    *(ushort4*)&Bh[prow][in0] = h4;
    *(ushort4*)&Bl[prow][in0] = l4;
    h4.x = bf16_hi(mac1.x); l4.x = bf16_rne(mac1.x - hi_f(mac1.x));
    h4.y = bf16_hi(mac1.y); l4.y = bf16_rne(mac1.y - hi_f(mac1.y));
    h4.z = bf16_hi(mac1.z); l4.z = bf16_rne(mac1.z - hi_f(mac1.z));
    h4.w = bf16_hi(mac1.w); l4.w = bf16_rne(mac1.w - hi_f(mac1.w));
    *(ushort4*)&Bh[prow][in0 + 4] = h4;
    *(ushort4*)&Bl[prow][in0 + 4] = l4;

    // Vt part: 32 rows x 64 inner; thread loads one float4
    const int vrow = tid >> 4, vin = 128 + (tid & 15) * 4;
    const float4 v = *(const float4*)&TMt[(size_t)(b * 16 + c) * 256 * 192 +
                                          (size_t)(cols0 + vrow) * 192 + vin];
    ushort4 vh, vl;
    vh.x = bf16_hi(v.x); vl.x = bf16_rne(v.x - hi_f(v.x));
    vh.y = bf16_hi(v.y); vl.y = bf16_rne(v.y - hi_f(v.y));
    vh.z = bf16_hi(v.z); vl.z = bf16_rne(v.z - hi_f(v.z));
    vh.w = bf16_hi(v.w); vl.w = bf16_rne(v.w - hi_f(v.w));
    *(ushort4*)&Bh[vrow][vin] = vh;
    *(ushort4*)&Bl[vrow][vin] = vl;
  }
  __syncthreads();

  // Phase 3: ret slice = A[64x192] . B[32][192]; 8 waves = (rt=w&3) x (ct=w>>2)
  {
    const int rt = w & 3;
    const int ct = w >> 2;   // 0..1
    float4v r2 = {};
#pragma unroll
    for (int kk = 0; kk < 6; ++kk) {
      const short8 ah = *(const short8*)&Ah[rt * 16 + m16][kk * 32 + quad * 8];
      const short8 al = *(const short8*)&Al[rt * 16 + m16][kk * 32 + quad * 8];
      const short8 bh = *(const short8*)&Bh[ct * 16 + m16][kk * 32 + quad * 8];
      const short8 bl = *(const short8*)&Bl[ct * 16 + m16][kk * 32 + quad * 8];
      r2 = __builtin_amdgcn_mfma_f32_16x16x32_bf16(ah, bh, r2, 0, 0, 0);
      r2 = __builtin_amdgcn_mfma_f32_16x16x32_bf16(ah, bl, r2, 0, 0, 0);
      r2 = __builtin_amdgcn_mfma_f32_16x16x32_bf16(al, bh, r2, 0, 0, 0);
    }
#pragma unroll
    for (int j = 0; j < 4; ++j) {
      const int rowL = rt * 16 + quad * 4 + j;
      const float nrm = rsqrtf((float)(c * 64 + rowL + 1) * 64.0f);
      const float v = r2[j] * nrm;
      ret[(size_t)(n0 + rowL) * D + cols0 + ct * 16 + m16] = v;
      float sj = v, s2j = v * v;
      for (int off = 1; off < 16; off <<= 1) {
        sj += __shfl_xor(sj, off, 64);
        s2j += __shfl_xor(s2j, off, 64);
      }
      if (m16 == 0) {
        LNred[(size_t)(n0 + rowL) * 32 + (dc * 2 + ct) * 2 + 0] = sj;
        LNred[(size_t)(n0 + rowL) * 32 + (dc * 2 + ct) * 2 + 1] = s2j;
      }
    }
  }
}

// ---------------------------------------------------------------------------
// K5: out = x + LN(ret).wo + bo via MFMA bf16x3. 256 blocks x 512 threads.
__global__ __launch_bounds__(512) void out2_kernel(
    const float* __restrict__ ret, const float* __restrict__ LNred,
    const float* __restrict__ x, const float* __restrict__ ln_g,
    const float* __restrict__ ln_b, const ushort* __restrict__ WT,
    const float* __restrict__ bo, float* __restrict__ out) {
  __shared__ __align__(16) ushort Ah[32][40], Al[32][40];
  __shared__ __align__(16) ushort Bh[64][40], Bl[64][40];
  __shared__ float mu_s[32], rs_s[32];
  const int tid = threadIdx.x;
  const int row0 = (blockIdx.x >> 2) * 32, nb = (blockIdx.x & 3) * 64;
  const ushort* Wh = WT + 3 * 131072;   // wo planes
  const ushort* Wl = Wh + 65536;
  const int w = tid >> 6, lane = tid & 63;
  const int m16 = lane & 15, quad = lane >> 4;
  const int rt = w & 1, cq = w >> 1;

  if (tid < 32) {
    const int row = row0 + tid;
    float s = 0.f, s2 = 0.f;
#pragma unroll
    for (int i = 0; i < 16; ++i) {
      s += LNred[(size_t)row * 32 + i * 2 + 0];
      s2 += LNred[(size_t)row * 32 + i * 2 + 1];
    }
    const float mu = s * (1.0f / 256.0f);
    mu_s[tid] = mu;
    rs_s[tid] = rsqrtf(s2 * (1.0f / 256.0f) - mu * mu + 1e-5f);
  }

  float4v acc = {};
  for (int k0 = 0; k0 < 256; k0 += 32) {
    __syncthreads();
    {
      const int r = tid >> 4, kc = (tid & 15) * 2;
      const float2 v = *(const float2*)&ret[(size_t)(row0 + r) * D + k0 + kc];
      const float2 g2 = *(const float2*)&ln_g[k0 + kc];
      const float2 b2 = *(const float2*)&ln_b[k0 + kc];
      const float mu = mu_s[r], rs = rs_s[r];
      const float a0 = (v.x - mu) * rs * g2.x + b2.x;
      const float a1 = (v.y - mu) * rs * g2.y + b2.y;
      ushort2 h2, l2;
      h2.x = bf16_hi(a0); l2.x = bf16_rne(a0 - hi_f(a0));
      h2.y = bf16_hi(a1); l2.y = bf16_rne(a1 - hi_f(a1));
      *(ushort2*)&Ah[r][kc] = h2;
      *(ushort2*)&Al[r][kc] = l2;
    }
    {
      const int plane = tid >> 8;
      const int n = (tid >> 2) & 63, chunk = tid & 3;
      const int ga = (nb + n) * 256 + k0 + chunk * 8;
      if (plane == 0) *(uint4*)&Bh[n][chunk * 8] = *(const uint4*)&Wh[ga];
      else            *(uint4*)&Bl[n][chunk * 8] = *(const uint4*)&Wl[ga];
    }
    __syncthreads();

    const short8 afh = *(const short8*)&Ah[rt * 16 + m16][quad * 8];
    const short8 afl = *(const short8*)&Al[rt * 16 + m16][quad * 8];
    const int col = cq * 16 + m16;
    const short8 bfh = *(const short8*)&Bh[col][quad * 8];
    const short8 bfl = *(const short8*)&Bl[col][quad * 8];
    acc = __builtin_amdgcn_mfma_f32_16x16x32_bf16(afh, bfh, acc, 0, 0, 0);
    acc = __builtin_amdgcn_mfma_f32_16x16x32_bf16(afh, bfl, acc, 0, 0, 0);
    acc = __builtin_amdgcn_mfma_f32_16x16x32_bf16(afl, bfh, acc, 0, 0, 0);
  }

  const int colg = nb + cq * 16 + m16;
  const float bias = bo[colg];
#pragma unroll
  for (int j = 0; j < 4; ++j) {
    const int rowg = row0 + rt * 16 + quad * 4 + j;
    out[rowg * D + colg] = x[rowg * D + colg] + acc[j] + bias;
  }
}

// ---------------------------------------------------------------------------
extern "C" void kernel_launch(void* const* d_in, const int* in_sizes, int n_in,
                              void* d_out, int out_size, void* d_ws, size_t ws_size,
                              hipStream_t stream) {
  (void)in_sizes; (void)n_in; (void)out_size; (void)ws_size;
  const float* x    = (const float*)d_in[0];
  const float* pos_k= (const float*)d_in[1];
  const float* w1_k = (const float*)d_in[2];
  const float* b1_k = (const float*)d_in[3];
  const float* w2_k = (const float*)d_in[4];
  const float* b2_k = (const float*)d_in[5];
  const float* wa_k = (const float*)d_in[6];
  const float* ba_k = (const float*)d_in[7];
  const float* pos_q= (const float*)d_in[8];
  const float* w1_q = (const float*)d_in[9];
  const float* b1_q = (const float*)d_in[10];
  const float* w2_q = (const float*)d_in[11];
  const float* b2_q = (const float*)d_in[12];
  const float* wa_q = (const float*)d_in[13];
  const float* ba_q = (const float*)d_in[14];
  const float* wv   = (const float*)d_in[15];
  const float* bv   = (const float*)d_in[16];
  const float* ln_g = (const float*)d_in[17];
  const float* ln_b = (const float*)d_in[18];
  const float* wo   = (const float*)d_in[19];
  const float* bo   = (const float*)d_in[20];

  float* ws = (float*)d_ws;
  float* kr = ws;                          // N*K
  float* ki = kr + (size_t)N * K;
  float* qr = ki + (size_t)N * K;
  float* qi = qr + (size_t)N * K;
  float* V  = qi + (size_t)N * K;          // N*D
  float* TMt = V + (size_t)N * D;          // B*NC*256*192
  float* ret = TMt + (size_t)B * NC * 256 * 192;  // N*D
  float* LNred = ret + (size_t)N * D;      // N*32
  float* hk = LNred + (size_t)N * 32;      // N*D
  float* hq = hk + (size_t)N * D;          // N*D
  ushort* WT = (ushort*)(hq + (size_t)N * D);   // 655360 ushorts

  prep_kernel<<<80, 256, 0, stream>>>(w1_k, w1_q, wv, wo,
                                      w2_k, wa_k, w2_q, wa_q, WT);
  enc1_kernel<<<384, 256, 0, stream>>>(x, pos_k, pos_q, b1_k, b1_q, bv, WT,
                                       hk, hq, V);
  enc2_kernel<<<256, 512, 0, stream>>>(x, pos_k, pos_q, hk, hq,
                                       b2_k, ba_k, b2_q, ba_q, WT,
                                       kr, ki, qr, qi);
  tbuild_kernel<<<B * NC * 16, 256, 0, stream>>>(kr, ki, V, TMt);
  ret_kernel<<<B * NC * 8, 512, 0, stream>>>(qr, qi, kr, ki, TMt, ret, LNred);
  out2_kernel<<<256, 512, 0, stream>>>(ret, LNred, x, ln_g, ln_b, WT, bo,
                                       (float*)d_out);
}